// Round 1
// baseline (8862.130 us; speedup 1.0000x reference)
//
#include <hip/hip_runtime.h>
#include <math.h>

// OLE loss on MI355X.
// Key reduction: singular values of X_c (n_c x 128) = sqrt(eig(G_c)) where
// G_c = X_c^T X_c is 128x128.  So: per-class Grams -> 65 symmetric 128x128
// eigenproblems (Jacobi, one block each) -> nuclear norms -> combine with CE.

#define N_ROWS 8192
#define DIM    128
#define NCLS   64
#define NSWEEP 8
#define LAMBDA_ 0.25f
#define DELTA_  1.0f

// XOR swizzle: row access (fixed i, consecutive j) and column access
// (fixed j, consecutive i) both hit all 32 banks -> conflict-free.
__device__ __forceinline__ int swz(int i, int j) {
  return (i << 7) + (j ^ (i & 31));
}

// Round-robin tournament pairing: round r (0..126), pair j (0..63).
// Covers all 128*127/2 pairs exactly once per sweep (127 prime).
__device__ __forceinline__ void pair_pq(int r, int j, int& p, int& q) {
  if (j == 0) {
    p = r; q = 127;
  } else {
    p = r + j; if (p >= 127) p -= 127;
    q = r - j; if (q < 0)   q += 127;
  }
}

// ---------------------------------------------------------------------------
// Kernel 1: per-class Gram matrices.  grid = 64 blocks (one per class),
// 256 threads as a 16x16 grid, each thread owns an 8x8 tile of G_c in regs.
// ---------------------------------------------------------------------------
__global__ __launch_bounds__(256) void ole_gram(const float* __restrict__ feat,
                                                const int* __restrict__ y,
                                                float* __restrict__ G) {
  const int c   = blockIdx.x;
  const int tid = threadIdx.x;
  const int ti  = tid >> 4, tj = tid & 15;
  const int i0  = ti * 8,  j0 = tj * 8;

  float acc[8][8];
#pragma unroll
  for (int a = 0; a < 8; ++a)
#pragma unroll
    for (int b = 0; b < 8; ++b) acc[a][b] = 0.f;

  __shared__ float xs[DIM];

  for (int r = 0; r < N_ROWS; ++r) {
    if (y[r] == c) {               // uniform branch (same r for whole block)
      __syncthreads();             // previous row fully consumed
      if (tid < DIM) xs[tid] = feat[r * DIM + tid];
      __syncthreads();
      float xi[8], xj[8];
#pragma unroll
      for (int a = 0; a < 8; ++a) xi[a] = xs[i0 + a];
#pragma unroll
      for (int b = 0; b < 8; ++b) xj[b] = xs[j0 + b];
#pragma unroll
      for (int a = 0; a < 8; ++a)
#pragma unroll
        for (int b = 0; b < 8; ++b) acc[a][b] = fmaf(xi[a], xj[b], acc[a][b]);
    }
  }

  float* Gc = G + (size_t)c * DIM * DIM;
  for (int a = 0; a < 8; ++a)
    for (int b = 0; b < 8; ++b)
      Gc[(i0 + a) * DIM + (j0 + b)] = acc[a][b];
}

// ---------------------------------------------------------------------------
// Kernel 2: cyclic Jacobi eigensolver, one block per matrix.  Block 64 builds
// G_all = sum_c G_c on load (feat^T feat).  Output: nuc[m] = sum sqrt(eig).
// ---------------------------------------------------------------------------
__global__ __launch_bounds__(256) void ole_jacobi(const float* __restrict__ G,
                                                  float* __restrict__ nuc) {
  __shared__ float A[DIM * DIM];   // 64 KB, XOR-swizzled
  __shared__ float cs_c[64], cs_s[64];
  __shared__ float wsum[4];

  const int m   = blockIdx.x;
  const int tid = threadIdx.x;

  if (m < NCLS) {
    for (int idx = tid; idx < DIM * DIM; idx += 256) {
      int i = idx >> 7, j = idx & 127;
      A[swz(i, j)] = G[(size_t)m * DIM * DIM + idx];
    }
  } else {
    for (int idx = tid; idx < DIM * DIM; idx += 256) {
      float s = 0.f;
      for (int c = 0; c < NCLS; ++c) s += G[(size_t)c * DIM * DIM + idx];
      int i = idx >> 7, j = idx & 127;
      A[swz(i, j)] = s;
    }
  }
  __syncthreads();

  for (int sweep = 0; sweep < NSWEEP; ++sweep) {
    for (int r = 0; r < 127; ++r) {
      // --- rotation angles (one thread per pair) ---
      if (tid < 64) {
        int p, q;
        pair_pq(r, tid, p, q);
        float app = A[swz(p, p)];
        float aqq = A[swz(q, q)];
        float apq = A[swz(p, q)];
        float cc = 1.f, ss = 0.f;
        if (fabsf(apq) > 1e-12f) {
          float tau = (aqq - app) / (2.f * apq);
          float t   = 1.f / (fabsf(tau) + sqrtf(1.f + tau * tau));
          if (tau < 0.f) t = -t;
          cc = rsqrtf(1.f + t * t);
          ss = t * cc;
        }
        cs_c[tid] = cc;
        cs_s[tid] = ss;
      }
      __syncthreads();

      // --- phase 1: A <- J^T A (rows p,q).  Pairs own disjoint rows. ---
      for (int it = tid; it < 64 * DIM; it += 256) {
        int j = it >> 7, k = it & 127;
        int p, q;
        pair_pq(r, j, p, q);
        float cc = cs_c[j], ss = cs_s[j];
        float ap = A[swz(p, k)], aq = A[swz(q, k)];
        A[swz(p, k)] = cc * ap - ss * aq;
        A[swz(q, k)] = ss * ap + cc * aq;
      }
      __syncthreads();

      // --- phase 2: A <- A J (cols p,q).  Pairs own disjoint cols. ---
      for (int it = tid; it < 64 * DIM; it += 256) {
        int j = it >> 7, k = it & 127;
        int p, q;
        pair_pq(r, j, p, q);
        float cc = cs_c[j], ss = cs_s[j];
        float ap = A[swz(k, p)], aq = A[swz(k, q)];
        A[swz(k, p)] = cc * ap - ss * aq;
        A[swz(k, q)] = ss * ap + cc * aq;
      }
      __syncthreads();
    }
  }

  // nuclear norm = sum sqrt(max(diag, 0))
  float local = (tid < DIM) ? sqrtf(fmaxf(A[swz(tid, tid)], 0.f)) : 0.f;
  for (int off = 32; off > 0; off >>= 1) local += __shfl_down(local, off, 64);
  if ((tid & 63) == 0) wsum[tid >> 6] = local;
  __syncthreads();
  if (tid == 0) nuc[m] = wsum[0] + wsum[1] + wsum[2] + wsum[3];
}

// ---------------------------------------------------------------------------
// Kernel 3: cross-entropy.  One wave per row (C = 64 = wave width).
// ---------------------------------------------------------------------------
__global__ __launch_bounds__(256) void ole_ce(const float* __restrict__ logits,
                                              const int* __restrict__ y,
                                              float* __restrict__ ce_sum) {
  const int gwave  = (blockIdx.x * 256 + threadIdx.x) >> 6;
  const int lane   = threadIdx.x & 63;
  const int nwaves = (gridDim.x * 256) >> 6;

  float acc = 0.f;
  for (int row = gwave; row < N_ROWS; row += nwaves) {
    float v = logits[row * NCLS + lane];
    float mx = v;
    for (int off = 32; off > 0; off >>= 1) mx = fmaxf(mx, __shfl_xor(mx, off, 64));
    float e = expf(v - mx);
    for (int off = 32; off > 0; off >>= 1) e += __shfl_xor(e, off, 64);
    if (lane == 0) {
      int t = y[row];
      acc += (mx + logf(e)) - logits[row * NCLS + t];
    }
  }
  if (lane == 0) atomicAdd(ce_sum, acc);
}

// ---------------------------------------------------------------------------
// Kernel 4: combine.  1 block, 64 threads.
// ---------------------------------------------------------------------------
__global__ void ole_final(const float* __restrict__ nuc,
                          const float* __restrict__ ce_sum,
                          float* __restrict__ out) {
  int tid = threadIdx.x;
  float v = fmaxf(nuc[tid], DELTA_);
  for (int off = 32; off > 0; off >>= 1) v += __shfl_down(v, off, 64);
  if (tid == 0) {
    float obj = v;                                   // sum_c max(nuc_c, DELTA)
    float ole = (obj - nuc[NCLS]) * (LAMBDA_ / (float)N_ROWS);
    out[0] = ole + ce_sum[0] / (float)N_ROWS;
  }
}

extern "C" void kernel_launch(void* const* d_in, const int* in_sizes, int n_in,
                              void* d_out, int out_size, void* d_ws, size_t ws_size,
                              hipStream_t stream) {
  const float* logits = (const float*)d_in[0];   // out [8192,64]
  const float* feat   = (const float*)d_in[1];   // feat [8192,128]
  const int*   y      = (const int*)d_in[2];     // y [8192]

  float* G   = (float*)d_ws;            // 64 * 16384 floats = 4 MB
  float* nuc = G + (size_t)NCLS * DIM * DIM;  // 65 floats
  float* ce  = nuc + NCLS + 1;          // 1 float

  hipMemsetAsync(ce, 0, sizeof(float), stream);
  ole_gram<<<NCLS, 256, 0, stream>>>(feat, y, G);
  ole_jacobi<<<NCLS + 1, 256, 0, stream>>>(G, nuc);
  ole_ce<<<32, 256, 0, stream>>>(logits, y, ce);
  ole_final<<<1, 64, 0, stream>>>(nuc, ce, (float*)d_out);
}

// Round 2
// 1000.808 us; speedup vs baseline: 8.8550x; 8.8550x over previous
//
#include <hip/hip_runtime.h>
#include <math.h>

// OLE loss on MI355X.
// Singular values of X_c = sqrt(eig(G_c)), G_c = X_c^T X_c (128x128).
// Per-class Grams -> 65 symmetric 128x128 Jacobi eigensolves (one block
// each, fused 2x2 block rotations, LDS-resident) -> nuclear norms -> + CE.

#define N_ROWS 8192
#define DIM    128
#define NCLS   64
#define NSWEEP 4
#define LAMBDA_ 0.25f
#define DELTA_  1.0f

// XOR swizzle: row-major with column index XORed by (row & 31).
// Fixed-row, consecutive-col accesses spread across all 32 banks.
__device__ __forceinline__ int swz(int i, int j) {
  return (i << 7) + (j ^ (i & 31));
}

// Round-robin tournament pairing: round r (0..126), pair j (0..63).
// Partitions indices 0..127 into 64 disjoint pairs each round; all
// 128*127/2 pairs covered once per sweep.
__device__ __forceinline__ void pair_pq(int r, int j, int& p, int& q) {
  if (j == 0) {
    p = r; q = 127;
  } else {
    p = r + j; if (p >= 127) p -= 127;
    q = r - j; if (q < 0)   q += 127;
  }
}

// ---------------------------------------------------------------------------
// Kernel 1: per-class Gram matrices. 64 blocks (one per class), 256 threads.
// Phase A: parallel compaction of matching row indices (order-invariant).
// Phase B: outer-product accumulation, 2 rows per iteration, 8x8 per thread.
// ---------------------------------------------------------------------------
__global__ __launch_bounds__(256) void ole_gram(const float* __restrict__ feat,
                                                const int* __restrict__ y,
                                                float* __restrict__ G) {
  __shared__ int   list[N_ROWS];   // 32 KB worst case
  __shared__ int   cnt;
  __shared__ float xs[2][DIM];

  const int c   = blockIdx.x;
  const int tid = threadIdx.x;
  const int ti  = tid >> 4, tj = tid & 15;
  const int i0  = ti * 8,  j0 = tj * 8;

  if (tid == 0) cnt = 0;
  __syncthreads();
  for (int r = tid; r < N_ROWS; r += 256) {
    if (y[r] == c) {
      int pos = atomicAdd(&cnt, 1);   // order irrelevant for the sum
      list[pos] = r;
    }
  }
  __syncthreads();
  const int n = cnt;

  float acc[8][8];
#pragma unroll
  for (int a = 0; a < 8; ++a)
#pragma unroll
    for (int b = 0; b < 8; ++b) acc[a][b] = 0.f;

  for (int base = 0; base < n; base += 2) {
    __syncthreads();                       // previous xs fully consumed
    {
      int which = tid >> 7, col = tid & 127;
      int li = base + which;
      xs[which][col] = (li < n) ? feat[(size_t)list[li] * DIM + col] : 0.f;
    }
    __syncthreads();
    float xi0[8], xj0[8], xi1[8], xj1[8];
#pragma unroll
    for (int a = 0; a < 8; ++a) { xi0[a] = xs[0][i0 + a]; xi1[a] = xs[1][i0 + a]; }
#pragma unroll
    for (int b = 0; b < 8; ++b) { xj0[b] = xs[0][j0 + b]; xj1[b] = xs[1][j0 + b]; }
#pragma unroll
    for (int a = 0; a < 8; ++a)
#pragma unroll
      for (int b = 0; b < 8; ++b) {
        acc[a][b] = fmaf(xi0[a], xj0[b], acc[a][b]);
        acc[a][b] = fmaf(xi1[a], xj1[b], acc[a][b]);
      }
  }

  float* Gc = G + (size_t)c * DIM * DIM;
#pragma unroll
  for (int a = 0; a < 8; ++a)
#pragma unroll
    for (int b = 0; b < 8; ++b)
      Gc[(i0 + a) * DIM + (j0 + b)] = acc[a][b];
}

// ---------------------------------------------------------------------------
// Kernel 2: cyclic Jacobi, one block per matrix, 1024 threads.
// Fused 2x2 block rotation: A <- J^T A J done as 64x64 disjoint 2x2 blocks,
// each element read+written exactly once per round; 2 barriers per round.
// Block 64 builds G_all = sum_c G_c on load. diag[] maintained analytically.
// ---------------------------------------------------------------------------
__global__ __launch_bounds__(1024) void ole_jacobi(const float* __restrict__ G,
                                                   float* __restrict__ nuc) {
  __shared__ float A[DIM * DIM];      // 64 KB, XOR-swizzled
  __shared__ float diag[DIM];
  __shared__ float cs_c[64], cs_s[64];
  __shared__ float red[16];

  const int m   = blockIdx.x;
  const int tid = threadIdx.x;

  if (m < NCLS) {
    const float* Gm = G + (size_t)m * DIM * DIM;
    for (int idx = tid; idx < DIM * DIM; idx += 1024) {
      int i = idx >> 7, j = idx & 127;
      A[swz(i, j)] = Gm[idx];
    }
  } else {
    for (int idx = tid; idx < DIM * DIM; idx += 1024) {
      float s = 0.f;
#pragma unroll 8
      for (int c = 0; c < NCLS; ++c) s += G[(size_t)c * DIM * DIM + idx];
      int i = idx >> 7, j = idx & 127;
      A[swz(i, j)] = s;
    }
  }
  __syncthreads();
  if (tid < DIM) diag[tid] = A[swz(tid, tid)];   // once; conflict cost trivial
  __syncthreads();

  for (int sweep = 0; sweep < NSWEEP; ++sweep) {
    for (int r = 0; r < 127; ++r) {
      // --- angles: one thread per pair; diag updated analytically ---
      if (tid < 64) {
        int p, q;
        pair_pq(r, tid, p, q);
        float app = diag[p], aqq = diag[q];
        float apq = A[swz(p, q)];
        float cc = 1.f, ss = 0.f, t = 0.f;
        if (fabsf(apq) > 1e-12f) {
          float tau = (aqq - app) / (2.f * apq);
          t = 1.f / (fabsf(tau) + sqrtf(1.f + tau * tau));
          if (tau < 0.f) t = -t;
          cc = rsqrtf(1.f + t * t);
          ss = t * cc;
        }
        cs_c[tid] = cc;
        cs_s[tid] = ss;
        diag[p] = app - t * apq;
        diag[q] = aqq + t * apq;
      }
      __syncthreads();

      // --- fused 2x2 block update: thread (j1,j2) owns rows {p1,q1} x
      //     cols {p2,q2}; reads and writes exactly those 4 elements. ---
      for (int it = tid; it < 64 * 64; it += 1024) {
        int j1 = it >> 6, j2 = it & 63;      // j1 wave-uniform, j2 = lane
        int p1, q1, p2, q2;
        pair_pq(r, j1, p1, q1);
        pair_pq(r, j2, p2, q2);
        float c1 = cs_c[j1], s1 = cs_s[j1];
        float c2 = cs_c[j2], s2 = cs_s[j2];
        int rb1 = p1 << 7, m1 = p1 & 31;
        int rb2 = q1 << 7, m2 = q1 & 31;
        int i00 = rb1 + (p2 ^ m1), i01 = rb1 + (q2 ^ m1);
        int i10 = rb2 + (p2 ^ m2), i11 = rb2 + (q2 ^ m2);
        float b00 = A[i00], b01 = A[i01];
        float b10 = A[i10], b11 = A[i11];
        // R1^T * B
        float t00 = c1 * b00 - s1 * b10;
        float t01 = c1 * b01 - s1 * b11;
        float t10 = s1 * b00 + c1 * b10;
        float t11 = s1 * b01 + c1 * b11;
        // (.) * R2
        A[i00] = c2 * t00 - s2 * t01;
        A[i01] = s2 * t00 + c2 * t01;
        A[i10] = c2 * t10 - s2 * t11;
        A[i11] = s2 * t10 + c2 * t11;
      }
      __syncthreads();
    }
  }

  // nuclear norm = sum sqrt(max(eig, 0)) from analytically-tracked diag
  float local = (tid < DIM) ? sqrtf(fmaxf(diag[tid], 0.f)) : 0.f;
  for (int off = 32; off > 0; off >>= 1) local += __shfl_down(local, off, 64);
  if ((tid & 63) == 0) red[tid >> 6] = local;
  __syncthreads();
  if (tid == 0) {
    float s = 0.f;
#pragma unroll
    for (int w = 0; w < 16; ++w) s += red[w];
    nuc[m] = s;
  }
}

// ---------------------------------------------------------------------------
// Kernel 3: cross-entropy. One wave per row (C = 64 = wave width).
// ---------------------------------------------------------------------------
__global__ __launch_bounds__(256) void ole_ce(const float* __restrict__ logits,
                                              const int* __restrict__ y,
                                              float* __restrict__ ce_sum) {
  const int gwave  = (blockIdx.x * 256 + threadIdx.x) >> 6;
  const int lane   = threadIdx.x & 63;
  const int nwaves = (gridDim.x * 256) >> 6;

  float acc = 0.f;
  for (int row = gwave; row < N_ROWS; row += nwaves) {
    float v = logits[row * NCLS + lane];
    float mx = v;
    for (int off = 32; off > 0; off >>= 1) mx = fmaxf(mx, __shfl_xor(mx, off, 64));
    float e = expf(v - mx);
    for (int off = 32; off > 0; off >>= 1) e += __shfl_xor(e, off, 64);
    if (lane == 0) {
      int t = y[row];
      acc += (mx + logf(e)) - logits[row * NCLS + t];
    }
  }
  if (lane == 0) atomicAdd(ce_sum, acc);
}

// ---------------------------------------------------------------------------
// Kernel 4: combine. 1 block, 64 threads.
// ---------------------------------------------------------------------------
__global__ void ole_final(const float* __restrict__ nuc,
                          const float* __restrict__ ce_sum,
                          float* __restrict__ out) {
  int tid = threadIdx.x;
  float v = fmaxf(nuc[tid], DELTA_);
  for (int off = 32; off > 0; off >>= 1) v += __shfl_down(v, off, 64);
  if (tid == 0) {
    float obj = v;                                   // sum_c max(nuc_c, DELTA)
    float ole = (obj - nuc[NCLS]) * (LAMBDA_ / (float)N_ROWS);
    out[0] = ole + ce_sum[0] / (float)N_ROWS;
  }
}

extern "C" void kernel_launch(void* const* d_in, const int* in_sizes, int n_in,
                              void* d_out, int out_size, void* d_ws, size_t ws_size,
                              hipStream_t stream) {
  const float* logits = (const float*)d_in[0];   // out  [8192,64]
  const float* feat   = (const float*)d_in[1];   // feat [8192,128]
  const int*   y      = (const int*)d_in[2];     // y    [8192]

  float* G   = (float*)d_ws;                     // 64 * 16384 floats = 4 MB
  float* nuc = G + (size_t)NCLS * DIM * DIM;     // 65 floats
  float* ce  = nuc + NCLS + 1;                   // 1 float

  hipMemsetAsync(ce, 0, sizeof(float), stream);
  ole_gram<<<NCLS, 256, 0, stream>>>(feat, y, G);
  ole_jacobi<<<NCLS + 1, 1024, 0, stream>>>(G, nuc);
  ole_ce<<<32, 256, 0, stream>>>(logits, y, ce);
  ole_final<<<1, 64, 0, stream>>>(nuc, ce, (float*)d_out);
}

// Round 3
// 837.743 us; speedup vs baseline: 10.5786x; 1.1946x over previous
//
#include <hip/hip_runtime.h>
#include <math.h>

// OLE loss on MI355X.
// Singular values of X_c = sqrt(eig(G_c)), G_c = X_c^T X_c (128x128).
// Per-class Grams -> 65 symmetric 128x128 Jacobi eigensolves (one block
// each, fused 2x2 block rotations, LDS-resident) -> nuclear norms -> + CE.
//
// R3: parallel-redundant angle phase (no serialized wave0 stage), full
// 16-read prefetch in the update, NSWEEP 3, vectorized gram staging.

#define N_ROWS 8192
#define DIM    128
#define NCLS   64
#define NSWEEP 3
#define LAMBDA_ 0.25f
#define DELTA_  1.0f

// XOR swizzle: row-major with column index XORed by (row & 31).
// Fixed-row, consecutive-col accesses spread across all 32 banks.
__device__ __forceinline__ int swz(int i, int j) {
  return (i << 7) + (j ^ (i & 31));
}

// Round-robin tournament pairing: round r (0..126), pair j (0..63).
// Partitions 0..127 into 64 disjoint pairs per round; all 128*127/2 pairs
// covered once per sweep (127 prime).
__device__ __forceinline__ void pair_pq(int r, int j, int& p, int& q) {
  if (j == 0) {
    p = r; q = 127;
  } else {
    p = r + j; if (p >= 127) p -= 127;
    q = r - j; if (q < 0)   q += 127;
  }
}

// ---------------------------------------------------------------------------
// Kernel 1: per-class Gram matrices. 64 blocks, 256 threads.
// Compaction of matching rows, then 8-row batches: float4 global->LDS
// staging, b128 LDS fragment reads, 8x8 register tile per thread.
// ---------------------------------------------------------------------------
__global__ __launch_bounds__(256) void ole_gram(const float* __restrict__ feat,
                                                const int* __restrict__ y,
                                                float* __restrict__ G) {
  __shared__ int   list[N_ROWS];     // 32 KB worst case
  __shared__ int   cnt;
  __shared__ float xs[8][DIM];       // 4 KB

  const int c   = blockIdx.x;
  const int tid = threadIdx.x;
  const int ti  = tid >> 4, tj = tid & 15;
  const int i0  = ti * 8,  j0 = tj * 8;

  if (tid == 0) cnt = 0;
  __syncthreads();
  for (int r = tid; r < N_ROWS; r += 256) {
    if (y[r] == c) {
      int pos = atomicAdd(&cnt, 1);  // order irrelevant for the sum
      list[pos] = r;
    }
  }
  __syncthreads();
  const int n = cnt;

  float acc[8][8];
#pragma unroll
  for (int a = 0; a < 8; ++a)
#pragma unroll
    for (int b = 0; b < 8; ++b) acc[a][b] = 0.f;

  const int ldrow = tid >> 5;        // 0..7: row within batch
  const int ldcol = (tid & 31) * 4;  // float4 column start

  for (int base = 0; base < n; base += 8) {
    __syncthreads();                 // previous xs fully consumed
    int li = base + ldrow;
    float4 v = make_float4(0.f, 0.f, 0.f, 0.f);
    if (li < n) v = *(const float4*)(feat + (size_t)list[li] * DIM + ldcol);
    *(float4*)(&xs[ldrow][ldcol]) = v;
    __syncthreads();
#pragma unroll
    for (int rw = 0; rw < 8; ++rw) {
      float xi[8], xj[8];
#pragma unroll
      for (int a = 0; a < 8; ++a) xi[a] = xs[rw][i0 + a];
#pragma unroll
      for (int b = 0; b < 8; ++b) xj[b] = xs[rw][j0 + b];
#pragma unroll
      for (int a = 0; a < 8; ++a)
#pragma unroll
        for (int b = 0; b < 8; ++b) acc[a][b] = fmaf(xi[a], xj[b], acc[a][b]);
    }
  }

  float* Gc = G + (size_t)c * DIM * DIM;
#pragma unroll
  for (int a = 0; a < 8; ++a)
#pragma unroll
    for (int b = 0; b < 8; ++b)
      Gc[(i0 + a) * DIM + (j0 + b)] = acc[a][b];
}

// ---------------------------------------------------------------------------
// Kernel 2: cyclic Jacobi, one block per matrix, 1024 threads (16 waves).
// Per round: [all waves redundantly compute all 64 angles in-register;
// wave0 maintains double-buffered diag] barrier [fused 2x2 block updates,
// 16 reads prefetched] barrier.  Block 64 builds G_all = sum_c G_c on load.
// ---------------------------------------------------------------------------
__global__ __launch_bounds__(1024) void ole_jacobi(const float* __restrict__ G,
                                                   float* __restrict__ nuc) {
  __shared__ float A[DIM * DIM];     // 64 KB, XOR-swizzled
  __shared__ float diag[2][DIM];
  __shared__ float red[16];

  const int m    = blockIdx.x;
  const int tid  = threadIdx.x;
  const int lane = tid & 63;
  const int wv   = __builtin_amdgcn_readfirstlane(tid >> 6);  // scalar wave id

  if (m < NCLS) {
    const float4* Gm = (const float4*)(G + (size_t)m * DIM * DIM);
    for (int idx4 = tid; idx4 < DIM * DIM / 4; idx4 += 1024) {
      float4 v = Gm[idx4];
      int idx = idx4 * 4;
      int i = idx >> 7, j = idx & 127, mk = i & 31, rb = i << 7;
      A[rb + ((j + 0) ^ mk)] = v.x;
      A[rb + ((j + 1) ^ mk)] = v.y;
      A[rb + ((j + 2) ^ mk)] = v.z;
      A[rb + ((j + 3) ^ mk)] = v.w;
    }
  } else {
    const float4* Gb = (const float4*)G;
    for (int idx4 = tid; idx4 < DIM * DIM / 4; idx4 += 1024) {
      float4 s = make_float4(0.f, 0.f, 0.f, 0.f);
#pragma unroll 8
      for (int c = 0; c < NCLS; ++c) {
        float4 v = Gb[(size_t)c * (DIM * DIM / 4) + idx4];
        s.x += v.x; s.y += v.y; s.z += v.z; s.w += v.w;
      }
      int idx = idx4 * 4;
      int i = idx >> 7, j = idx & 127, mk = i & 31, rb = i << 7;
      A[rb + ((j + 0) ^ mk)] = s.x;
      A[rb + ((j + 1) ^ mk)] = s.y;
      A[rb + ((j + 2) ^ mk)] = s.z;
      A[rb + ((j + 3) ^ mk)] = s.w;
    }
  }
  __syncthreads();
  if (tid < DIM) diag[0][tid] = A[swz(tid, tid)];  // one-time; conflicts trivial
  __syncthreads();

  int buf = 0;
  for (int sweep = 0; sweep < NSWEEP; ++sweep) {
    for (int r = 0; r < 127; ++r) {
      // --- angles: each wave computes all 64 in its lanes (redundant) ---
      int p, q;
      pair_pq(r, lane, p, q);
      float app = diag[buf][p], aqq = diag[buf][q];
      float apq = A[swz(p, q)];
      float cc = 1.f, ss = 0.f, t = 0.f;
      if (fabsf(apq) > 1e-12f) {
        float tau = (aqq - app) / (2.f * apq);
        t = 1.f / (fabsf(tau) + sqrtf(1.f + tau * tau));
        if (tau < 0.f) t = -t;
        cc = rsqrtf(1.f + t * t);
        ss = t * cc;
      }
      if (wv == 0) {                 // maintain diag analytically, dbl-buffered
        diag[buf ^ 1][p] = app - t * apq;
        diag[buf ^ 1][q] = aqq + t * apq;
      }
      buf ^= 1;
      __syncthreads();               // apq/diag reads done before A writes

      // --- fused 2x2 updates: 4 independent blocks/thread, reads prefetched.
      //     cols = own lane's pair (p,q), c2/s2 = own (cc,ss);
      //     rows = pair j1 = wv+16k, c1/s1 via wave shuffle. ---
      int   ad[4][4];
      float b[4][4];
#pragma unroll
      for (int k = 0; k < 4; ++k) {
        int j1 = wv + 16 * k;
        int p1, q1;
        pair_pq(r, j1, p1, q1);
        int rb1 = p1 << 7, m1 = p1 & 31;
        int rb2 = q1 << 7, m2 = q1 & 31;
        ad[k][0] = rb1 + (p ^ m1);
        ad[k][1] = rb1 + (q ^ m1);
        ad[k][2] = rb2 + (p ^ m2);
        ad[k][3] = rb2 + (q ^ m2);
        b[k][0] = A[ad[k][0]];
        b[k][1] = A[ad[k][1]];
        b[k][2] = A[ad[k][2]];
        b[k][3] = A[ad[k][3]];
      }
#pragma unroll
      for (int k = 0; k < 4; ++k) {
        int j1 = wv + 16 * k;
        float c1 = __shfl(cc, j1, 64);
        float s1 = __shfl(ss, j1, 64);
        float t00 = c1 * b[k][0] - s1 * b[k][2];
        float t01 = c1 * b[k][1] - s1 * b[k][3];
        float t10 = s1 * b[k][0] + c1 * b[k][2];
        float t11 = s1 * b[k][1] + c1 * b[k][3];
        A[ad[k][0]] = cc * t00 - ss * t01;
        A[ad[k][1]] = ss * t00 + cc * t01;
        A[ad[k][2]] = cc * t10 - ss * t11;
        A[ad[k][3]] = ss * t10 + cc * t11;
      }
      __syncthreads();               // A writes done before next angle reads
    }
  }

  // nuclear norm = sum sqrt(max(eig, 0)) from tracked diag
  float local = (tid < DIM) ? sqrtf(fmaxf(diag[buf][tid], 0.f)) : 0.f;
  for (int off = 32; off > 0; off >>= 1) local += __shfl_down(local, off, 64);
  if ((tid & 63) == 0) red[tid >> 6] = local;
  __syncthreads();
  if (tid == 0) {
    float s = 0.f;
#pragma unroll
    for (int w = 0; w < 16; ++w) s += red[w];
    nuc[m] = s;
  }
}

// ---------------------------------------------------------------------------
// Kernel 3: cross-entropy. One wave per row (C = 64 = wave width).
// ---------------------------------------------------------------------------
__global__ __launch_bounds__(256) void ole_ce(const float* __restrict__ logits,
                                              const int* __restrict__ y,
                                              float* __restrict__ ce_sum) {
  const int gwave  = (blockIdx.x * 256 + threadIdx.x) >> 6;
  const int lane   = threadIdx.x & 63;
  const int nwaves = (gridDim.x * 256) >> 6;

  float acc = 0.f;
  for (int row = gwave; row < N_ROWS; row += nwaves) {
    float v = logits[row * NCLS + lane];
    float mx = v;
    for (int off = 32; off > 0; off >>= 1) mx = fmaxf(mx, __shfl_xor(mx, off, 64));
    float e = expf(v - mx);
    for (int off = 32; off > 0; off >>= 1) e += __shfl_xor(e, off, 64);
    if (lane == 0) {
      int t = y[row];
      acc += (mx + logf(e)) - logits[row * NCLS + t];
    }
  }
  if (lane == 0) atomicAdd(ce_sum, acc);
}

// ---------------------------------------------------------------------------
// Kernel 4: combine. 1 block, 64 threads.
// ---------------------------------------------------------------------------
__global__ void ole_final(const float* __restrict__ nuc,
                          const float* __restrict__ ce_sum,
                          float* __restrict__ out) {
  int tid = threadIdx.x;
  float v = fmaxf(nuc[tid], DELTA_);
  for (int off = 32; off > 0; off >>= 1) v += __shfl_down(v, off, 64);
  if (tid == 0) {
    float obj = v;                                   // sum_c max(nuc_c, DELTA)
    float ole = (obj - nuc[NCLS]) * (LAMBDA_ / (float)N_ROWS);
    out[0] = ole + ce_sum[0] / (float)N_ROWS;
  }
}

extern "C" void kernel_launch(void* const* d_in, const int* in_sizes, int n_in,
                              void* d_out, int out_size, void* d_ws, size_t ws_size,
                              hipStream_t stream) {
  const float* logits = (const float*)d_in[0];   // out  [8192,64]
  const float* feat   = (const float*)d_in[1];   // feat [8192,128]
  const int*   y      = (const int*)d_in[2];     // y    [8192]

  float* G   = (float*)d_ws;                     // 64 * 16384 floats = 4 MB
  float* nuc = G + (size_t)NCLS * DIM * DIM;     // 65 floats
  float* ce  = nuc + NCLS + 1;                   // 1 float

  hipMemsetAsync(ce, 0, sizeof(float), stream);
  ole_gram<<<NCLS, 256, 0, stream>>>(feat, y, G);
  ole_jacobi<<<NCLS + 1, 1024, 0, stream>>>(G, nuc);
  ole_ce<<<128, 256, 0, stream>>>(logits, y, ce);
  ole_final<<<1, 64, 0, stream>>>(nuc, ce, (float*)d_out);
}

// Round 5
// 229.129 us; speedup vs baseline: 38.6775x; 3.6562x over previous
//
#include <hip/hip_runtime.h>
#include <math.h>

// OLE loss on MI355X.
// ||X_c||* = trace(sqrt(G_c)), G_c = X_c^T X_c (128x128).
// Coupled Newton-Schulz on bf16 MFMA, one block per matrix.
// R5 precision fix: Y,M in split bf16 (hi+lo ~ 2^-17), Z single bf16;
// Frobenius normalization (safe lambda_max bound); trace anchored on fp32 G.

#define N_ROWS 8192
#define DIM    128
#define NCLS   64
#define NMAT   65
#define NITER  13
#define EPSN   2e-4f
#define LAMBDA_ 0.25f
#define DELTA_  1.0f

typedef __attribute__((ext_vector_type(8))) short s16x8;  // 8 bf16 = 4 VGPR
typedef __attribute__((ext_vector_type(4))) short s16x4;  // 4 bf16
typedef __attribute__((ext_vector_type(4))) float f32x4;

__device__ __forceinline__ unsigned short f2bf(float f) {   // RNE
  unsigned u = __float_as_uint(f);
  u = (u + 0x7FFFu + ((u >> 16) & 1u)) >> 16;
  return (unsigned short)u;
}
__device__ __forceinline__ float bf2f(unsigned short h) {
  return __uint_as_float(((unsigned)h) << 16);
}

// bf16 LDS: element (i,j) at short-index i*128 + (((j>>3)^(i&15))<<3) + (j&7)
// 16B-group XOR swizzle -> all b128/b64 frag accesses 2-way per bank (free).
__device__ __forceinline__ int swz_idx(int i, int j) {
  return i * 128 + (((j >> 3) ^ (i & 15)) << 3) + (j & 7);
}

// MFMA 16x16x32 A/B fragment: lane holds 8 contiguous k at row (lane&15),
// kgroup = 4*kstep + (lane>>4).  Near-symmetric matrices: same loader
// serves A (direct) and B (transposed) reads.
__device__ __forceinline__ s16x8 load_frag(const short* buf, int row0,
                                           int kstep, int lane) {
  int m  = row0 + (lane & 15);
  int kg = kstep * 4 + (lane >> 4);
  return *(const s16x8*)(buf + m * 128 + ((kg ^ (m & 15)) << 3));
}

// ---------------------------------------------------------------------------
// Kernel 1: per-class Gram matrices (proven in R3/R4).
// ---------------------------------------------------------------------------
__global__ __launch_bounds__(256) void ole_gram(const float* __restrict__ feat,
                                                const int* __restrict__ y,
                                                float* __restrict__ G) {
  __shared__ int   list[N_ROWS];
  __shared__ int   cnt;
  __shared__ float xs[8][DIM];

  const int c   = blockIdx.x;
  const int tid = threadIdx.x;
  const int ti  = tid >> 4, tj = tid & 15;
  const int i0  = ti * 8,  j0 = tj * 8;

  if (tid == 0) cnt = 0;
  __syncthreads();
  for (int r = tid; r < N_ROWS; r += 256) {
    if (y[r] == c) {
      int pos = atomicAdd(&cnt, 1);
      list[pos] = r;
    }
  }
  __syncthreads();
  const int n = cnt;

  float acc[8][8];
#pragma unroll
  for (int a = 0; a < 8; ++a)
#pragma unroll
    for (int b = 0; b < 8; ++b) acc[a][b] = 0.f;

  const int ldrow = tid >> 5;
  const int ldcol = (tid & 31) * 4;

  for (int base = 0; base < n; base += 8) {
    __syncthreads();
    int li = base + ldrow;
    float4 v = make_float4(0.f, 0.f, 0.f, 0.f);
    if (li < n) v = *(const float4*)(feat + (size_t)list[li] * DIM + ldcol);
    *(float4*)(&xs[ldrow][ldcol]) = v;
    __syncthreads();
#pragma unroll
    for (int rw = 0; rw < 8; ++rw) {
      float xi[8], xj[8];
#pragma unroll
      for (int a = 0; a < 8; ++a) xi[a] = xs[rw][i0 + a];
#pragma unroll
      for (int b = 0; b < 8; ++b) xj[b] = xs[rw][j0 + b];
#pragma unroll
      for (int a = 0; a < 8; ++a)
#pragma unroll
        for (int b = 0; b < 8; ++b) acc[a][b] = fmaf(xi[a], xj[b], acc[a][b]);
    }
  }

  float* Gc = G + (size_t)c * DIM * DIM;
#pragma unroll
  for (int a = 0; a < 8; ++a)
#pragma unroll
    for (int b = 0; b < 8; ++b)
      Gc[(i0 + a) * DIM + (j0 + b)] = acc[a][b];
}

// ---------------------------------------------------------------------------
// Kernel 1b: G_all = sum_c G_c.
// ---------------------------------------------------------------------------
__global__ __launch_bounds__(256) void ole_sumg(const float* __restrict__ G,
                                                float* __restrict__ Gall) {
  int idx = blockIdx.x * 256 + threadIdx.x;
  const float4* G4 = (const float4*)G;
  float4 s = make_float4(0.f, 0.f, 0.f, 0.f);
#pragma unroll 8
  for (int c = 0; c < NCLS; ++c) {
    float4 v = G4[(size_t)c * (DIM * DIM / 4) + idx];
    s.x += v.x; s.y += v.y; s.z += v.z; s.w += v.w;
  }
  ((float4*)Gall)[idx] = s;
}

// ---------------------------------------------------------------------------
// Kernel 1c: per-matrix trace and ||.||_F^2  -> stats[2m], stats[2m+1].
// ---------------------------------------------------------------------------
__global__ __launch_bounds__(256) void ole_prep(const float* __restrict__ G,
                                                float* __restrict__ stats) {
  __shared__ float ra[4], rb[4];
  const int m = blockIdx.x, tid = threadIdx.x;
  const float4* Gm = (const float4*)(G + (size_t)m * DIM * DIM);
  float tr = 0.f, fr = 0.f;
  for (int idx4 = tid; idx4 < DIM * DIM / 4; idx4 += 256) {
    float4 v = Gm[idx4];
    fr += v.x * v.x + v.y * v.y + v.z * v.z + v.w * v.w;
    int flat = idx4 * 4, i = flat >> 7, j0 = flat & 127;
    if (j0 <= i && i < j0 + 4) tr += ((const float*)&v)[i - j0];
  }
  for (int off = 32; off > 0; off >>= 1) {
    tr += __shfl_down(tr, off, 64);
    fr += __shfl_down(fr, off, 64);
  }
  int wv = tid >> 6;
  if ((tid & 63) == 0) { ra[wv] = tr; rb[wv] = fr; }
  __syncthreads();
  if (tid == 0) {
    stats[2 * m]     = ra[0] + ra[1] + ra[2] + ra[3];
    stats[2 * m + 1] = rb[0] + rb[1] + rb[2] + rb[3];
  }
}

// ---------------------------------------------------------------------------
// Kernel 2: coupled Newton-Schulz, one block (512 thr, 8 waves) per matrix.
// S = G/||G||_F + eps*I, eps = 2e-4 * trace/||G||_F.
// Iter: W = Z*Y ; M = 1.5I - 0.5W (clamped, hi/lo) ; Y' = Y*M ; Z' = M*Z.
// Output: nuc = sqrt(s) * [ (1/s)tr(GZ) + (eps/2)tr(Z) - (eps^2/8)tr(Z^3) ].
// LDS: Yh,Yl,Mh,Ml (split) + Z (single) = 5 x 32KB = 160 KiB exactly.
// ---------------------------------------------------------------------------
__global__ __launch_bounds__(512, 2) void ole_ns(const float* __restrict__ G,
                                                 const float* __restrict__ stats,
                                                 float* __restrict__ nuc) {
  __shared__ short Yh[DIM * DIM];
  __shared__ short Yl[DIM * DIM];
  __shared__ short Mh[DIM * DIM];
  __shared__ short Ml[DIM * DIM];
  __shared__ short Zb[DIM * DIM];

  const int m_id = blockIdx.x;
  const int tid  = threadIdx.x;
  const int lane = tid & 63;
  const int quad = lane >> 4;
  const int wv   = tid >> 6;
  const int wr   = wv >> 2;     // 0..1 -> 4 tile-rows
  const int wc   = wv & 3;      // 0..3 -> 2 tile-cols

  const float*  Gm  = G + (size_t)m_id * DIM * DIM;
  const float4* Gm4 = (const float4*)Gm;

  float trace = stats[2 * m_id], fro2 = stats[2 * m_id + 1];
  float s = sqrtf(fro2);
  if (s < 1e-12f) s = 1.f;
  const float invs = 1.f / s;
  const float eps  = EPSN * trace * invs;

  // ---- init: Y0 = G/s + eps*I (hi/lo), Z0 = I ----
#pragma unroll
  for (int t = 0; t < 8; ++t) {
    int idx4 = tid + 512 * t;
    int flat = idx4 * 4, i = flat >> 7, j0 = flat & 127;
    float4 v = Gm4[idx4];
    s16x4 vh, vl;
#pragma unroll
    for (int e = 0; e < 4; ++e) {
      float x = ((const float*)&v)[e] * invs + ((i == j0 + e) ? eps : 0.f);
      unsigned short hh = f2bf(x);
      vh[e] = (short)hh;
      vl[e] = (short)f2bf(x - bf2f(hh));
    }
    int idx = swz_idx(i, j0);
    *(s16x4*)(Yh + idx) = vh;
    *(s16x4*)(Yl + idx) = vl;
  }
  for (int grp = tid; grp < DIM * 16; grp += 512) {
    int i = grp >> 4, g = grp & 15;
    s16x8 v = (s16x8)0;
    if ((i >> 3) == g) v[i & 7] = (short)0x3F80;   // 1.0 bf16
    *(s16x8*)(Zb + i * 128 + ((g ^ (i & 15)) << 3)) = v;
  }
  __syncthreads();

  for (int it = 0; it < NITER; ++it) {
    // --- (a) W = Z*Y ---
    f32x4 acc[4][2];
#pragma unroll
    for (int r = 0; r < 4; ++r)
#pragma unroll
      for (int c2 = 0; c2 < 2; ++c2) acc[r][c2] = (f32x4)0.f;
#pragma unroll
    for (int ks = 0; ks < 4; ++ks) {
      s16x8 a[4], bh[2], bl[2];
#pragma unroll
      for (int r = 0; r < 4; ++r) a[r] = load_frag(Zb, (4 * wr + r) * 16, ks, lane);
#pragma unroll
      for (int c2 = 0; c2 < 2; ++c2) {
        bh[c2] = load_frag(Yh, (2 * wc + c2) * 16, ks, lane);
        bl[c2] = load_frag(Yl, (2 * wc + c2) * 16, ks, lane);
      }
#pragma unroll
      for (int r = 0; r < 4; ++r)
#pragma unroll
        for (int c2 = 0; c2 < 2; ++c2) {
          acc[r][c2] = __builtin_amdgcn_mfma_f32_16x16x32_bf16(a[r], bh[c2], acc[r][c2], 0, 0, 0);
          acc[r][c2] = __builtin_amdgcn_mfma_f32_16x16x32_bf16(a[r], bl[c2], acc[r][c2], 0, 0, 0);
        }
    }
    // --- (b) M = 1.5I - 0.5W, clamp, hi/lo split, transposed store ---
#pragma unroll
    for (int r = 0; r < 4; ++r) {
      int ibase = (4 * wr + r) * 16 + quad * 4;
      int cg    = ibase >> 3;
#pragma unroll
      for (int c2 = 0; c2 < 2; ++c2) {
        int jg  = (2 * wc + c2) * 16 + (lane & 15);
        int idx = jg * 128 + ((cg ^ (jg & 15)) << 3) + (ibase & 7);
        s16x4 vh, vl;
#pragma unroll
        for (int e = 0; e < 4; ++e) {
          float mv = -0.5f * acc[r][c2][e] + ((ibase + e == jg) ? 1.5f : 0.f);
          mv = fminf(fmaxf(mv, -4.f), 4.f);        // runaway insurance
          unsigned short hh = f2bf(mv);
          vh[e] = (short)hh;
          vl[e] = (short)f2bf(mv - bf2f(hh));
        }
        *(s16x4*)(Mh + idx) = vh;
        *(s16x4*)(Ml + idx) = vl;
      }
    }
    __syncthreads();

    // --- (c) Y' = Y*M (3 products), Z' = M*Z (2 products) ---
    f32x4 ay[4][2], az[4][2];
#pragma unroll
    for (int r = 0; r < 4; ++r)
#pragma unroll
      for (int c2 = 0; c2 < 2; ++c2) { ay[r][c2] = (f32x4)0.f; az[r][c2] = (f32x4)0.f; }
#pragma unroll
    for (int ks = 0; ks < 4; ++ks) {
      s16x8 aYh[4], aYl[4], aMh[4], aMl[4], bMh[2], bMl[2], bZ[2];
#pragma unroll
      for (int r = 0; r < 4; ++r) {
        int rb = (4 * wr + r) * 16;
        aYh[r] = load_frag(Yh, rb, ks, lane);
        aYl[r] = load_frag(Yl, rb, ks, lane);
        aMh[r] = load_frag(Mh, rb, ks, lane);
        aMl[r] = load_frag(Ml, rb, ks, lane);
      }
#pragma unroll
      for (int c2 = 0; c2 < 2; ++c2) {
        int cb = (2 * wc + c2) * 16;
        bMh[c2] = load_frag(Mh, cb, ks, lane);
        bMl[c2] = load_frag(Ml, cb, ks, lane);
        bZ[c2]  = load_frag(Zb, cb, ks, lane);
      }
#pragma unroll
      for (int r = 0; r < 4; ++r)
#pragma unroll
        for (int c2 = 0; c2 < 2; ++c2) {
          ay[r][c2] = __builtin_amdgcn_mfma_f32_16x16x32_bf16(aYh[r], bMh[c2], ay[r][c2], 0, 0, 0);
          ay[r][c2] = __builtin_amdgcn_mfma_f32_16x16x32_bf16(aYh[r], bMl[c2], ay[r][c2], 0, 0, 0);
          ay[r][c2] = __builtin_amdgcn_mfma_f32_16x16x32_bf16(aYl[r], bMh[c2], ay[r][c2], 0, 0, 0);
          az[r][c2] = __builtin_amdgcn_mfma_f32_16x16x32_bf16(aMh[r], bZ[c2],  az[r][c2], 0, 0, 0);
          az[r][c2] = __builtin_amdgcn_mfma_f32_16x16x32_bf16(aMl[r], bZ[c2],  az[r][c2], 0, 0, 0);
        }
    }
    __syncthreads();   // all reads of Y,Z done

    // --- (d) store Y' (hi/lo), Z' (single), transposed ---
#pragma unroll
    for (int r = 0; r < 4; ++r) {
      int ibase = (4 * wr + r) * 16 + quad * 4;
      int cg    = ibase >> 3;
#pragma unroll
      for (int c2 = 0; c2 < 2; ++c2) {
        int jg  = (2 * wc + c2) * 16 + (lane & 15);
        int idx = jg * 128 + ((cg ^ (jg & 15)) << 3) + (ibase & 7);
        s16x4 vh, vl, vz;
#pragma unroll
        for (int e = 0; e < 4; ++e) {
          float yv = ay[r][c2][e];
          unsigned short hh = f2bf(yv);
          vh[e] = (short)hh;
          vl[e] = (short)f2bf(yv - bf2f(hh));
          vz[e] = (short)f2bf(az[r][c2][e]);
        }
        *(s16x4*)(Yh + idx) = vh;
        *(s16x4*)(Yl + idx) = vl;
        *(s16x4*)(Zb + idx) = vz;
      }
    }
    __syncthreads();
  }

  // ---- traces: tr(GZ) (fp32 G anchor), tr(Z), tr(Z^3) ----
  float t_gz = 0.f, t_z = 0.f, t_z3 = 0.f;
#pragma unroll
  for (int t = 0; t < 8; ++t) {
    int idx4 = tid + 512 * t;
    int flat = idx4 * 4, i = flat >> 7, j0 = flat & 127;
    float4 g = Gm4[idx4];
    s16x4 zv = *(const s16x4*)(Zb + swz_idx(i, j0));
#pragma unroll
    for (int e = 0; e < 4; ++e) t_gz += ((const float*)&g)[e] * bf2f((unsigned short)zv[e]);
  }
  if (tid < DIM) t_z = bf2f((unsigned short)Zb[swz_idx(tid, tid)]);

  {  // U = Z*Z tile-wise; tr(Z^3) = sum U_ij * Z_ji
    f32x4 u[4][2];
#pragma unroll
    for (int r = 0; r < 4; ++r)
#pragma unroll
      for (int c2 = 0; c2 < 2; ++c2) u[r][c2] = (f32x4)0.f;
#pragma unroll
    for (int ks = 0; ks < 4; ++ks) {
      s16x8 a[4], b[2];
#pragma unroll
      for (int r = 0; r < 4; ++r) a[r] = load_frag(Zb, (4 * wr + r) * 16, ks, lane);
#pragma unroll
      for (int c2 = 0; c2 < 2; ++c2) b[c2] = load_frag(Zb, (2 * wc + c2) * 16, ks, lane);
#pragma unroll
      for (int r = 0; r < 4; ++r)
#pragma unroll
        for (int c2 = 0; c2 < 2; ++c2)
          u[r][c2] = __builtin_amdgcn_mfma_f32_16x16x32_bf16(a[r], b[c2], u[r][c2], 0, 0, 0);
    }
#pragma unroll
    for (int r = 0; r < 4; ++r) {
      int ibase = (4 * wr + r) * 16 + quad * 4;
      int cg    = ibase >> 3;
#pragma unroll
      for (int c2 = 0; c2 < 2; ++c2) {
        int jg  = (2 * wc + c2) * 16 + (lane & 15);
        int idx = jg * 128 + ((cg ^ (jg & 15)) << 3) + (ibase & 7);
        s16x4 zt = *(const s16x4*)(Zb + idx);
#pragma unroll
        for (int e = 0; e < 4; ++e) t_z3 += u[r][c2][e] * bf2f((unsigned short)zt[e]);
      }
    }
  }

  // block reduction (reuse Mh as scratch — no longer needed)
  for (int off = 32; off > 0; off >>= 1) {
    t_gz += __shfl_down(t_gz, off, 64);
    t_z  += __shfl_down(t_z,  off, 64);
    t_z3 += __shfl_down(t_z3, off, 64);
  }
  __syncthreads();
  float* red = (float*)Mh;
  if (lane == 0) { red[wv] = t_gz; red[8 + wv] = t_z; red[16 + wv] = t_z3; }
  __syncthreads();
  if (tid == 0) {
    float gz = 0.f, z1 = 0.f, z3 = 0.f;
#pragma unroll
    for (int w = 0; w < 8; ++w) { gz += red[w]; z1 += red[8 + w]; z3 += red[16 + w]; }
    float trsq = gz * invs + 0.5f * eps * z1 - 0.125f * eps * eps * z3;
    nuc[m_id] = sqrtf(s) * trsq;
  }
}

// ---------------------------------------------------------------------------
// Kernel 3: cross-entropy. One wave per row (C = 64 = wave width).
// ---------------------------------------------------------------------------
__global__ __launch_bounds__(256) void ole_ce(const float* __restrict__ logits,
                                              const int* __restrict__ y,
                                              float* __restrict__ ce_sum) {
  const int gwave  = (blockIdx.x * 256 + threadIdx.x) >> 6;
  const int lane   = threadIdx.x & 63;
  const int nwaves = (gridDim.x * 256) >> 6;

  float acc = 0.f;
  for (int row = gwave; row < N_ROWS; row += nwaves) {
    float v = logits[row * NCLS + lane];
    float mx = v;
    for (int off = 32; off > 0; off >>= 1) mx = fmaxf(mx, __shfl_xor(mx, off, 64));
    float e = expf(v - mx);
    for (int off = 32; off > 0; off >>= 1) e += __shfl_xor(e, off, 64);
    if (lane == 0) {
      int t = y[row];
      acc += (mx + logf(e)) - logits[row * NCLS + t];
    }
  }
  if (lane == 0) atomicAdd(ce_sum, acc);
}

// ---------------------------------------------------------------------------
// Kernel 4: combine.
// ---------------------------------------------------------------------------
__global__ void ole_final(const float* __restrict__ nuc,
                          const float* __restrict__ ce_sum,
                          float* __restrict__ out) {
  int tid = threadIdx.x;
  float v = fmaxf(nuc[tid], DELTA_);
  for (int off = 32; off > 0; off >>= 1) v += __shfl_down(v, off, 64);
  if (tid == 0) {
    float ole = (v - nuc[NCLS]) * (LAMBDA_ / (float)N_ROWS);
    out[0] = ole + ce_sum[0] / (float)N_ROWS;
  }
}

extern "C" void kernel_launch(void* const* d_in, const int* in_sizes, int n_in,
                              void* d_out, int out_size, void* d_ws, size_t ws_size,
                              hipStream_t stream) {
  const float* logits = (const float*)d_in[0];   // out  [8192,64]
  const float* feat   = (const float*)d_in[1];   // feat [8192,128]
  const int*   y      = (const int*)d_in[2];     // y    [8192]

  float* G     = (float*)d_ws;                         // 64 class mats
  float* Gall  = G + (size_t)NCLS * DIM * DIM;         // matrix index 64
  float* stats = G + (size_t)NMAT * DIM * DIM;         // 130 floats
  float* nuc   = stats + 2 * NMAT;                     // 65 floats
  float* ce    = nuc + NMAT;                           // 1 float

  hipMemsetAsync(ce, 0, sizeof(float), stream);
  ole_gram<<<NCLS, 256, 0, stream>>>(feat, y, G);
  ole_sumg<<<16, 256, 0, stream>>>(G, Gall);
  ole_prep<<<NMAT, 256, 0, stream>>>(G, stats);
  ole_ns<<<NMAT, 512, 0, stream>>>(G, stats, nuc);
  ole_ce<<<128, 256, 0, stream>>>(logits, y, ce);
  ole_final<<<1, 64, 0, stream>>>(nuc, ce, (float*)d_out);
}

// Round 6
// 211.446 us; speedup vs baseline: 41.9121x; 1.0836x over previous
//
#include <hip/hip_runtime.h>
#include <math.h>

// OLE loss on MI355X.
// ||X_c||* = trace(sqrt(G_c)), G_c = X_c^T X_c (128x128).
// Coupled Newton-Schulz on bf16 MFMA, one block per matrix.
// Y,M split bf16 (hi+lo ~2^-17), Z single bf16; Frobenius normalization;
// trace anchored on fp32 G with 2nd-order eps-bias correction.
// R6: 2x2 wave grid (4 waves, 4x4 tiles each) -> 0.67x LDS reads;
// fused dispatches (gram+ce, sumg+prep).

#define N_ROWS 8192
#define DIM    128
#define NCLS   64
#define NMAT   65
#define NITER  13
#define EPSN   2e-4f
#define LAMBDA_ 0.25f
#define DELTA_  1.0f

typedef __attribute__((ext_vector_type(8))) short s16x8;  // 8 bf16 = 4 VGPR
typedef __attribute__((ext_vector_type(4))) short s16x4;  // 4 bf16
typedef __attribute__((ext_vector_type(4))) float f32x4;

__device__ __forceinline__ unsigned short f2bf(float f) {   // RNE
  unsigned u = __float_as_uint(f);
  u = (u + 0x7FFFu + ((u >> 16) & 1u)) >> 16;
  return (unsigned short)u;
}
__device__ __forceinline__ float bf2f(unsigned short h) {
  return __uint_as_float(((unsigned)h) << 16);
}

// bf16 LDS: element (i,j) at short-index i*128 + (((j>>3)^(i&15))<<3) + (j&7)
// 16B-group XOR swizzle -> all b128/b64 frag accesses 2-way per bank (free).
__device__ __forceinline__ int swz_idx(int i, int j) {
  return i * 128 + (((j >> 3) ^ (i & 15)) << 3) + (j & 7);
}

// MFMA 16x16x32 A/B fragment: lane holds 8 contiguous k at row (lane&15),
// kgroup = 4*kstep + (lane>>4).  Symmetric iterates: same loader serves A
// (direct) and B (transposed) reads.
__device__ __forceinline__ s16x8 load_frag(const short* buf, int row0,
                                           int kstep, int lane) {
  int m  = row0 + (lane & 15);
  int kg = kstep * 4 + (lane >> 4);
  return *(const s16x8*)(buf + m * 128 + ((kg ^ (m & 15)) << 3));
}

// ---------------------------------------------------------------------------
// Kernel 1: blocks 0..63 = per-class Gram; blocks 64..191 = cross-entropy.
// ---------------------------------------------------------------------------
__global__ __launch_bounds__(256) void ole_gram_ce(const float* __restrict__ feat,
                                                   const int* __restrict__ y,
                                                   const float* __restrict__ logits,
                                                   float* __restrict__ G,
                                                   float* __restrict__ ce_sum) {
  __shared__ int   list[N_ROWS];
  __shared__ int   cnt;
  __shared__ float xs[8][DIM];

  const int tid = threadIdx.x;

  if (blockIdx.x >= NCLS) {
    // ---------------- cross-entropy path (128 blocks) ----------------
    const int blk    = blockIdx.x - NCLS;
    const int gwave  = (blk * 256 + tid) >> 6;
    const int lane   = tid & 63;
    const int nwaves = (128 * 256) >> 6;

    float acc = 0.f;
    for (int row = gwave; row < N_ROWS; row += nwaves) {
      float v = logits[row * NCLS + lane];
      float mx = v;
      for (int off = 32; off > 0; off >>= 1) mx = fmaxf(mx, __shfl_xor(mx, off, 64));
      float e = expf(v - mx);
      for (int off = 32; off > 0; off >>= 1) e += __shfl_xor(e, off, 64);
      if (lane == 0) {
        int t = y[row];
        acc += (mx + logf(e)) - logits[row * NCLS + t];
      }
    }
    if (lane == 0) atomicAdd(ce_sum, acc);
    return;
  }

  // ---------------- gram path (64 blocks) ----------------
  const int c  = blockIdx.x;
  const int ti = tid >> 4, tj = tid & 15;
  const int i0 = ti * 8,  j0 = tj * 8;

  if (tid == 0) cnt = 0;
  __syncthreads();
  const int4* y4 = (const int4*)y;
#pragma unroll
  for (int t = 0; t < 8; ++t) {
    int g4 = tid + 256 * t;
    int4 v = y4[g4];
    int r0 = g4 * 4;
    if (v.x == c) list[atomicAdd(&cnt, 1)] = r0;
    if (v.y == c) list[atomicAdd(&cnt, 1)] = r0 + 1;
    if (v.z == c) list[atomicAdd(&cnt, 1)] = r0 + 2;
    if (v.w == c) list[atomicAdd(&cnt, 1)] = r0 + 3;
  }
  __syncthreads();
  const int n = cnt;

  float acc[8][8];
#pragma unroll
  for (int a = 0; a < 8; ++a)
#pragma unroll
    for (int b = 0; b < 8; ++b) acc[a][b] = 0.f;

  const int ldrow = tid >> 5;
  const int ldcol = (tid & 31) * 4;

  for (int base = 0; base < n; base += 8) {
    __syncthreads();
    int li = base + ldrow;
    float4 v = make_float4(0.f, 0.f, 0.f, 0.f);
    if (li < n) v = *(const float4*)(feat + (size_t)list[li] * DIM + ldcol);
    *(float4*)(&xs[ldrow][ldcol]) = v;
    __syncthreads();
#pragma unroll
    for (int rw = 0; rw < 8; ++rw) {
      float xi[8], xj[8];
#pragma unroll
      for (int a = 0; a < 8; ++a) xi[a] = xs[rw][i0 + a];
#pragma unroll
      for (int b = 0; b < 8; ++b) xj[b] = xs[rw][j0 + b];
#pragma unroll
      for (int a = 0; a < 8; ++a)
#pragma unroll
        for (int b = 0; b < 8; ++b) acc[a][b] = fmaf(xi[a], xj[b], acc[a][b]);
    }
  }

  float* Gc = G + (size_t)c * DIM * DIM;
#pragma unroll
  for (int a = 0; a < 8; ++a)
#pragma unroll
    for (int b = 0; b < 8; ++b)
      Gc[(i0 + a) * DIM + (j0 + b)] = acc[a][b];
}

// ---------------------------------------------------------------------------
// Kernel 2: blocks 0..63: per-class trace/fro2 -> stats[2m..].
// blocks 64..79: build Gall slice (sum of 64 class mats) + atomicAdd its
// trace/fro2 partials into stats[128],stats[129] (zeroed by memset).
// ---------------------------------------------------------------------------
__global__ __launch_bounds__(256) void ole_prep(const float* __restrict__ G,
                                                float* __restrict__ Gall,
                                                float* __restrict__ stats) {
  __shared__ float ra[4], rb[4];
  const int tid = threadIdx.x;
  const int wv  = tid >> 6;

  if (blockIdx.x < NCLS) {
    const int m = blockIdx.x;
    const float4* Gm = (const float4*)(G + (size_t)m * DIM * DIM);
    float tr = 0.f, fr = 0.f;
    for (int idx4 = tid; idx4 < DIM * DIM / 4; idx4 += 256) {
      float4 v = Gm[idx4];
      fr += v.x * v.x + v.y * v.y + v.z * v.z + v.w * v.w;
      int flat = idx4 * 4, i = flat >> 7, j0 = flat & 127;
      if (j0 <= i && i < j0 + 4) tr += ((const float*)&v)[i - j0];
    }
    for (int off = 32; off > 0; off >>= 1) {
      tr += __shfl_down(tr, off, 64);
      fr += __shfl_down(fr, off, 64);
    }
    if ((tid & 63) == 0) { ra[wv] = tr; rb[wv] = fr; }
    __syncthreads();
    if (tid == 0) {
      stats[2 * m]     = ra[0] + ra[1] + ra[2] + ra[3];
      stats[2 * m + 1] = rb[0] + rb[1] + rb[2] + rb[3];
    }
  } else {
    const int b    = blockIdx.x - NCLS;       // 0..15
    const int idx4 = b * 256 + tid;           // 0..4095
    const float4* G4 = (const float4*)G;
    float4 s = make_float4(0.f, 0.f, 0.f, 0.f);
#pragma unroll 8
    for (int c = 0; c < NCLS; ++c) {
      float4 v = G4[(size_t)c * (DIM * DIM / 4) + idx4];
      s.x += v.x; s.y += v.y; s.z += v.z; s.w += v.w;
    }
    ((float4*)Gall)[idx4] = s;
    float fr = s.x * s.x + s.y * s.y + s.z * s.z + s.w * s.w;
    float tr = 0.f;
    int flat = idx4 * 4, i = flat >> 7, j0 = flat & 127;
    if (j0 <= i && i < j0 + 4) tr = ((const float*)&s)[i - j0];
    for (int off = 32; off > 0; off >>= 1) {
      tr += __shfl_down(tr, off, 64);
      fr += __shfl_down(fr, off, 64);
    }
    if ((tid & 63) == 0) { ra[wv] = tr; rb[wv] = fr; }
    __syncthreads();
    if (tid == 0) {
      atomicAdd(&stats[2 * NCLS],     ra[0] + ra[1] + ra[2] + ra[3]);
      atomicAdd(&stats[2 * NCLS + 1], rb[0] + rb[1] + rb[2] + rb[3]);
    }
  }
}

// ---------------------------------------------------------------------------
// Kernel 3: coupled Newton-Schulz, one block (256 thr, 4 waves) per matrix.
// Wave grid 2x2, each wave owns 4x4 tiles of 16x16 -> minimal cross-wave
// fragment re-reads (LDS is the binding pipe).
// S = G/||G||_F + eps*I, eps = 2e-4 * trace/||G||_F.
// Iter: W = Z*Y ; M = 1.5I - 0.5W (clamped, hi/lo) ; Y' = Y*M ; Z' = M*Z.
// Output: nuc = sqrt(s) * [ (1/s)tr(GZ) + (eps/2)tr(Z) - (eps^2/8)tr(Z^3) ].
// LDS: Yh,Yl,Mh,Ml,Z = 5 x 32KB = 160 KiB (1 block/CU).
// ---------------------------------------------------------------------------
__global__ __launch_bounds__(256, 1) void ole_ns(const float* __restrict__ G,
                                                 const float* __restrict__ stats,
                                                 float* __restrict__ nuc) {
  __shared__ short Yh[DIM * DIM];
  __shared__ short Yl[DIM * DIM];
  __shared__ short Mh[DIM * DIM];
  __shared__ short Ml[DIM * DIM];
  __shared__ short Zb[DIM * DIM];

  const int m_id = blockIdx.x;
  const int tid  = threadIdx.x;
  const int lane = tid & 63;
  const int quad = lane >> 4;
  const int wv   = tid >> 6;    // 0..3
  const int wr   = wv >> 1;     // 0..1 -> tile-rows 4*wr..4*wr+3
  const int wc   = wv & 1;      // 0..1 -> tile-cols 4*wc..4*wc+3

  const float4* Gm4 = (const float4*)(G + (size_t)m_id * DIM * DIM);

  float trace = stats[2 * m_id], fro2 = stats[2 * m_id + 1];
  float s = sqrtf(fro2);
  if (s < 1e-12f) s = 1.f;
  const float invs = 1.f / s;
  const float eps  = EPSN * trace * invs;

  // ---- init: Y0 = G/s + eps*I (hi/lo), Z0 = I ----
#pragma unroll
  for (int t = 0; t < 16; ++t) {
    int idx4 = tid + 256 * t;
    int flat = idx4 * 4, i = flat >> 7, j0 = flat & 127;
    float4 v = Gm4[idx4];
    s16x4 vh, vl;
#pragma unroll
    for (int e = 0; e < 4; ++e) {
      float x = ((const float*)&v)[e] * invs + ((i == j0 + e) ? eps : 0.f);
      unsigned short hh = f2bf(x);
      vh[e] = (short)hh;
      vl[e] = (short)f2bf(x - bf2f(hh));
    }
    int idx = swz_idx(i, j0);
    *(s16x4*)(Yh + idx) = vh;
    *(s16x4*)(Yl + idx) = vl;
  }
  for (int grp = tid; grp < DIM * 16; grp += 256) {
    int i = grp >> 4, g = grp & 15;
    s16x8 v = (s16x8)0;
    if ((i >> 3) == g) v[i & 7] = (short)0x3F80;   // 1.0 bf16
    *(s16x8*)(Zb + i * 128 + ((g ^ (i & 15)) << 3)) = v;
  }
  __syncthreads();

  for (int it = 0; it < NITER; ++it) {
    // --- (a) W = Z*Y (Yh+Yl) ---
    f32x4 acc[4][4];
#pragma unroll
    for (int r = 0; r < 4; ++r)
#pragma unroll
      for (int c2 = 0; c2 < 4; ++c2) acc[r][c2] = (f32x4)0.f;
#pragma unroll
    for (int ks = 0; ks < 4; ++ks) {
      s16x8 a[4], bh[4], bl[4];
#pragma unroll
      for (int r = 0; r < 4; ++r) a[r] = load_frag(Zb, (4 * wr + r) * 16, ks, lane);
#pragma unroll
      for (int c2 = 0; c2 < 4; ++c2) {
        bh[c2] = load_frag(Yh, (4 * wc + c2) * 16, ks, lane);
        bl[c2] = load_frag(Yl, (4 * wc + c2) * 16, ks, lane);
      }
#pragma unroll
      for (int r = 0; r < 4; ++r)
#pragma unroll
        for (int c2 = 0; c2 < 4; ++c2) {
          acc[r][c2] = __builtin_amdgcn_mfma_f32_16x16x32_bf16(a[r], bh[c2], acc[r][c2], 0, 0, 0);
          acc[r][c2] = __builtin_amdgcn_mfma_f32_16x16x32_bf16(a[r], bl[c2], acc[r][c2], 0, 0, 0);
        }
    }
    // --- (b) M = 1.5I - 0.5W, clamp, hi/lo split, transposed store ---
#pragma unroll
    for (int r = 0; r < 4; ++r) {
      int ibase = (4 * wr + r) * 16 + quad * 4;
      int cg    = ibase >> 3;
#pragma unroll
      for (int c2 = 0; c2 < 4; ++c2) {
        int jg  = (4 * wc + c2) * 16 + (lane & 15);
        int idx = jg * 128 + ((cg ^ (jg & 15)) << 3) + (ibase & 7);
        s16x4 vh, vl;
#pragma unroll
        for (int e = 0; e < 4; ++e) {
          float mv = -0.5f * acc[r][c2][e] + ((ibase + e == jg) ? 1.5f : 0.f);
          mv = fminf(fmaxf(mv, -4.f), 4.f);        // runaway insurance
          unsigned short hh = f2bf(mv);
          vh[e] = (short)hh;
          vl[e] = (short)f2bf(mv - bf2f(hh));
        }
        *(s16x4*)(Mh + idx) = vh;
        *(s16x4*)(Ml + idx) = vl;
      }
    }
    __syncthreads();

    // --- (c) Y' = Y*M (3 products), Z' = M*Z (2 products) ---
    f32x4 ay[4][4], az[4][4];
#pragma unroll
    for (int r = 0; r < 4; ++r)
#pragma unroll
      for (int c2 = 0; c2 < 4; ++c2) { ay[r][c2] = (f32x4)0.f; az[r][c2] = (f32x4)0.f; }
#pragma unroll
    for (int ks = 0; ks < 4; ++ks) {
      s16x8 aYh[4], aYl[4], aMh[4], aMl[4], bMh[4], bMl[4], bZ[4];
#pragma unroll
      for (int r = 0; r < 4; ++r) {
        int rb = (4 * wr + r) * 16;
        aYh[r] = load_frag(Yh, rb, ks, lane);
        aYl[r] = load_frag(Yl, rb, ks, lane);
        aMh[r] = load_frag(Mh, rb, ks, lane);
        aMl[r] = load_frag(Ml, rb, ks, lane);
      }
#pragma unroll
      for (int c2 = 0; c2 < 4; ++c2) {
        int cb = (4 * wc + c2) * 16;
        bMh[c2] = load_frag(Mh, cb, ks, lane);
        bMl[c2] = load_frag(Ml, cb, ks, lane);
        bZ[c2]  = load_frag(Zb, cb, ks, lane);
      }
#pragma unroll
      for (int r = 0; r < 4; ++r)
#pragma unroll
        for (int c2 = 0; c2 < 4; ++c2) {
          ay[r][c2] = __builtin_amdgcn_mfma_f32_16x16x32_bf16(aYh[r], bMh[c2], ay[r][c2], 0, 0, 0);
          ay[r][c2] = __builtin_amdgcn_mfma_f32_16x16x32_bf16(aYh[r], bMl[c2], ay[r][c2], 0, 0, 0);
          ay[r][c2] = __builtin_amdgcn_mfma_f32_16x16x32_bf16(aYl[r], bMh[c2], ay[r][c2], 0, 0, 0);
          az[r][c2] = __builtin_amdgcn_mfma_f32_16x16x32_bf16(aMh[r], bZ[c2],  az[r][c2], 0, 0, 0);
          az[r][c2] = __builtin_amdgcn_mfma_f32_16x16x32_bf16(aMl[r], bZ[c2],  az[r][c2], 0, 0, 0);
        }
    }
    __syncthreads();   // all reads of Y,Z done

    // --- (d) store Y' (hi/lo), Z' (single), transposed ---
#pragma unroll
    for (int r = 0; r < 4; ++r) {
      int ibase = (4 * wr + r) * 16 + quad * 4;
      int cg    = ibase >> 3;
#pragma unroll
      for (int c2 = 0; c2 < 4; ++c2) {
        int jg  = (4 * wc + c2) * 16 + (lane & 15);
        int idx = jg * 128 + ((cg ^ (jg & 15)) << 3) + (ibase & 7);
        s16x4 vh, vl, vz;
#pragma unroll
        for (int e = 0; e < 4; ++e) {
          float yv = ay[r][c2][e];
          unsigned short hh = f2bf(yv);
          vh[e] = (short)hh;
          vl[e] = (short)f2bf(yv - bf2f(hh));
          vz[e] = (short)f2bf(az[r][c2][e]);
        }
        *(s16x4*)(Yh + idx) = vh;
        *(s16x4*)(Yl + idx) = vl;
        *(s16x4*)(Zb + idx) = vz;
      }
    }
    __syncthreads();
  }

  // ---- traces: tr(GZ) (fp32 G anchor), tr(Z), tr(Z^3) ----
  float t_gz = 0.f, t_z = 0.f, t_z3 = 0.f;
#pragma unroll
  for (int t = 0; t < 16; ++t) {
    int idx4 = tid + 256 * t;
    int flat = idx4 * 4, i = flat >> 7, j0 = flat & 127;
    float4 g = Gm4[idx4];
    s16x4 zv = *(const s16x4*)(Zb + swz_idx(i, j0));
#pragma unroll
    for (int e = 0; e < 4; ++e) t_gz += ((const float*)&g)[e] * bf2f((unsigned short)zv[e]);
  }
  if (tid < DIM) t_z = bf2f((unsigned short)Zb[swz_idx(tid, tid)]);

  {  // U = Z*Z tile-wise; tr(Z^3) = sum U_ij * Z_ji
    f32x4 u[4][4];
#pragma unroll
    for (int r = 0; r < 4; ++r)
#pragma unroll
      for (int c2 = 0; c2 < 4; ++c2) u[r][c2] = (f32x4)0.f;
#pragma unroll
    for (int ks = 0; ks < 4; ++ks) {
      s16x8 a[4], b[4];
#pragma unroll
      for (int r = 0; r < 4; ++r) a[r] = load_frag(Zb, (4 * wr + r) * 16, ks, lane);
#pragma unroll
      for (int c2 = 0; c2 < 4; ++c2) b[c2] = load_frag(Zb, (4 * wc + c2) * 16, ks, lane);
#pragma unroll
      for (int r = 0; r < 4; ++r)
#pragma unroll
        for (int c2 = 0; c2 < 4; ++c2)
          u[r][c2] = __builtin_amdgcn_mfma_f32_16x16x32_bf16(a[r], b[c2], u[r][c2], 0, 0, 0);
    }
#pragma unroll
    for (int r = 0; r < 4; ++r) {
      int ibase = (4 * wr + r) * 16 + quad * 4;
      int cg    = ibase >> 3;
#pragma unroll
      for (int c2 = 0; c2 < 4; ++c2) {
        int jg  = (4 * wc + c2) * 16 + (lane & 15);
        int idx = jg * 128 + ((cg ^ (jg & 15)) << 3) + (ibase & 7);
        s16x4 zt = *(const s16x4*)(Zb + idx);
#pragma unroll
        for (int e = 0; e < 4; ++e) t_z3 += u[r][c2][e] * bf2f((unsigned short)zt[e]);
      }
    }
  }

  // block reduction (reuse Mh as scratch)
  for (int off = 32; off > 0; off >>= 1) {
    t_gz += __shfl_down(t_gz, off, 64);
    t_z  += __shfl_down(t_z,  off, 64);
    t_z3 += __shfl_down(t_z3, off, 64);
  }
  __syncthreads();
  float* red = (float*)Mh;
  if (lane == 0) { red[wv] = t_gz; red[4 + wv] = t_z; red[8 + wv] = t_z3; }
  __syncthreads();
  if (tid == 0) {
    float gz = 0.f, z1 = 0.f, z3 = 0.f;
#pragma unroll
    for (int w = 0; w < 4; ++w) { gz += red[w]; z1 += red[4 + w]; z3 += red[8 + w]; }
    float trsq = gz * invs + 0.5f * eps * z1 - 0.125f * eps * eps * z3;
    nuc[m_id] = sqrtf(s) * trsq;
  }
}

// ---------------------------------------------------------------------------
// Kernel 4: combine.
// ---------------------------------------------------------------------------
__global__ void ole_final(const float* __restrict__ nuc,
                          const float* __restrict__ ce_sum,
                          float* __restrict__ out) {
  int tid = threadIdx.x;
  float v = fmaxf(nuc[tid], DELTA_);
  for (int off = 32; off > 0; off >>= 1) v += __shfl_down(v, off, 64);
  if (tid == 0) {
    float ole = (v - nuc[NCLS]) * (LAMBDA_ / (float)N_ROWS);
    out[0] = ole + ce_sum[0] / (float)N_ROWS;
  }
}

extern "C" void kernel_launch(void* const* d_in, const int* in_sizes, int n_in,
                              void* d_out, int out_size, void* d_ws, size_t ws_size,
                              hipStream_t stream) {
  const float* logits = (const float*)d_in[0];   // out  [8192,64]
  const float* feat   = (const float*)d_in[1];   // feat [8192,128]
  const int*   y      = (const int*)d_in[2];     // y    [8192]

  float* G     = (float*)d_ws;                         // 64 class mats
  float* Gall  = G + (size_t)NCLS * DIM * DIM;         // matrix index 64 (contiguous)
  float* stats = G + (size_t)NMAT * DIM * DIM;         // 130 floats
  float* nuc   = stats + 2 * NMAT;                     // 65 floats
  float* ce    = nuc + NMAT;                           // 1 float

  // zero stats + nuc + ce in one shot (stats[128/129] and ce are accumulated)
  hipMemsetAsync(stats, 0, (2 * NMAT + NMAT + 1) * sizeof(float), stream);
  ole_gram_ce<<<NCLS + 128, 256, 0, stream>>>(feat, y, logits, G, ce);
  ole_prep<<<NCLS + 16, 256, 0, stream>>>(G, Gall, stats);
  ole_ns<<<NMAT, 256, 0, stream>>>(G, stats, nuc);
  ole_final<<<1, 64, 0, stream>>>(nuc, ce, (float*)d_out);
}

// Round 7
// 158.921 us; speedup vs baseline: 55.7642x; 1.3305x over previous
//
#include <hip/hip_runtime.h>
#include <math.h>

// OLE loss on MI355X.
// ||X_c||* = trace(sqrt(G_c)), G_c = X_c^T X_c (128x128).
// Coupled Newton-Schulz on bf16 MFMA, one block per matrix.
// Y,M split bf16 (hi+lo ~2^-17), Z single bf16; Frobenius normalization;
// trace anchored on fp32 G with 2nd-order eps-bias correction.
// R7: scaled-NS coefficient ladder (t_k) -> NITER 13->9; 8-wave geometry
// (2 waves/SIMD latency hiding, proven R5); stats fused into ole_ns;
// memset eliminated (CE partial slots).

#define N_ROWS 8192
#define DIM    128
#define NCLS   64
#define NMAT   65
#define NITER  9
#define EPSN   2e-4f
#define LAMBDA_ 0.25f
#define DELTA_  1.0f

typedef __attribute__((ext_vector_type(8))) short s16x8;  // 8 bf16 = 4 VGPR
typedef __attribute__((ext_vector_type(4))) short s16x4;  // 4 bf16
typedef __attribute__((ext_vector_type(4))) float f32x4;

// Scaled-NS ladder: M_k = C1[k]*I - C2[k]*W, C1 = 1.5*sqrt(t), C2 = 0.5*t^1.5.
// t = [2.9, 2.758, 2.13, 1.868, 1.264, 1, 1, 1, 1].  Map w' = u(1.5-u/2)^2,
// u = t*w: max over (0,3) is exactly 1, so t*hi <= 2.91 < 3 keeps every mode
// sign-safe; final t=1 steps polish to the true fixed point w=1.
static __device__ const float NS_C1[NITER] =
  {2.554408f, 2.491084f, 2.189178f, 2.050122f, 1.686417f, 1.5f, 1.5f, 1.5f, 1.5f};
static __device__ const float NS_C2[NITER] =
  {2.469261f, 2.290137f, 1.554316f, 1.276543f, 0.710544f, 0.5f, 0.5f, 0.5f, 0.5f};

__device__ __forceinline__ unsigned short f2bf(float f) {   // RNE
  unsigned u = __float_as_uint(f);
  u = (u + 0x7FFFu + ((u >> 16) & 1u)) >> 16;
  return (unsigned short)u;
}
__device__ __forceinline__ float bf2f(unsigned short h) {
  return __uint_as_float(((unsigned)h) << 16);
}

// bf16 LDS: element (i,j) at short-index i*128 + (((j>>3)^(i&15))<<3) + (j&7)
// 16B-group XOR swizzle -> all b128/b64 frag accesses 2-way per bank (free).
__device__ __forceinline__ int swz_idx(int i, int j) {
  return i * 128 + (((j >> 3) ^ (i & 15)) << 3) + (j & 7);
}

// MFMA 16x16x32 A/B fragment: lane holds 8 contiguous k at row (lane&15),
// kgroup = 4*kstep + (lane>>4).  Symmetric iterates: same loader serves A
// (direct) and B (transposed) reads.
__device__ __forceinline__ s16x8 load_frag(const short* buf, int row0,
                                           int kstep, int lane) {
  int m  = row0 + (lane & 15);
  int kg = kstep * 4 + (lane >> 4);
  return *(const s16x8*)(buf + m * 128 + ((kg ^ (m & 15)) << 3));
}

// ---------------------------------------------------------------------------
// Kernel 1: blocks 0..63 = per-class Gram; blocks 64..191 = cross-entropy
// (per-wave partials into cepart[512], no atomics, no pre-zeroing).
// ---------------------------------------------------------------------------
__global__ __launch_bounds__(256) void ole_gram_ce(const float* __restrict__ feat,
                                                   const int* __restrict__ y,
                                                   const float* __restrict__ logits,
                                                   float* __restrict__ G,
                                                   float* __restrict__ cepart) {
  __shared__ int   list[N_ROWS];
  __shared__ int   cnt;
  __shared__ float xs[8][DIM];

  const int tid = threadIdx.x;

  if (blockIdx.x >= NCLS) {
    // ---------------- cross-entropy path (128 blocks, 512 waves) ----------
    const int blk    = blockIdx.x - NCLS;
    const int gwave  = blk * 4 + (tid >> 6);
    const int lane   = tid & 63;

    float acc = 0.f;
    for (int row = gwave; row < N_ROWS; row += 512) {
      float v = logits[row * NCLS + lane];
      float mx = v;
      for (int off = 32; off > 0; off >>= 1) mx = fmaxf(mx, __shfl_xor(mx, off, 64));
      float e = expf(v - mx);
      for (int off = 32; off > 0; off >>= 1) e += __shfl_xor(e, off, 64);
      if (lane == 0) {
        int t = y[row];
        acc += (mx + logf(e)) - logits[row * NCLS + t];
      }
    }
    if (lane == 0) cepart[gwave] = acc;
    return;
  }

  // ---------------- gram path (64 blocks) ----------------
  const int c  = blockIdx.x;
  const int ti = tid >> 4, tj = tid & 15;
  const int i0 = ti * 8,  j0 = tj * 8;

  if (tid == 0) cnt = 0;
  __syncthreads();
  const int4* y4 = (const int4*)y;
#pragma unroll
  for (int t = 0; t < 8; ++t) {
    int g4 = tid + 256 * t;
    int4 v = y4[g4];
    int r0 = g4 * 4;
    if (v.x == c) list[atomicAdd(&cnt, 1)] = r0;
    if (v.y == c) list[atomicAdd(&cnt, 1)] = r0 + 1;
    if (v.z == c) list[atomicAdd(&cnt, 1)] = r0 + 2;
    if (v.w == c) list[atomicAdd(&cnt, 1)] = r0 + 3;
  }
  __syncthreads();
  const int n = cnt;

  float acc[8][8];
#pragma unroll
  for (int a = 0; a < 8; ++a)
#pragma unroll
    for (int b = 0; b < 8; ++b) acc[a][b] = 0.f;

  const int ldrow = tid >> 5;
  const int ldcol = (tid & 31) * 4;

  for (int base = 0; base < n; base += 8) {
    __syncthreads();
    int li = base + ldrow;
    float4 v = make_float4(0.f, 0.f, 0.f, 0.f);
    if (li < n) v = *(const float4*)(feat + (size_t)list[li] * DIM + ldcol);
    *(float4*)(&xs[ldrow][ldcol]) = v;
    __syncthreads();
#pragma unroll
    for (int rw = 0; rw < 8; ++rw) {
      float xi[8], xj[8];
#pragma unroll
      for (int a = 0; a < 8; ++a) xi[a] = xs[rw][i0 + a];
#pragma unroll
      for (int b = 0; b < 8; ++b) xj[b] = xs[rw][j0 + b];
#pragma unroll
      for (int a = 0; a < 8; ++a)
#pragma unroll
        for (int b = 0; b < 8; ++b) acc[a][b] = fmaf(xi[a], xj[b], acc[a][b]);
    }
  }

  float* Gc = G + (size_t)c * DIM * DIM;
#pragma unroll
  for (int a = 0; a < 8; ++a)
#pragma unroll
    for (int b = 0; b < 8; ++b)
      Gc[(i0 + a) * DIM + (j0 + b)] = acc[a][b];
}

// ---------------------------------------------------------------------------
// Kernel 2: Gall = sum_c G_c (16 blocks x 256 threads, direct writes).
// ---------------------------------------------------------------------------
__global__ __launch_bounds__(256) void ole_gall(const float* __restrict__ G,
                                                float* __restrict__ Gall) {
  int idx4 = blockIdx.x * 256 + threadIdx.x;       // 0..4095
  const float4* G4 = (const float4*)G;
  float4 s = make_float4(0.f, 0.f, 0.f, 0.f);
#pragma unroll 8
  for (int c = 0; c < NCLS; ++c) {
    float4 v = G4[(size_t)c * (DIM * DIM / 4) + idx4];
    s.x += v.x; s.y += v.y; s.z += v.z; s.w += v.w;
  }
  ((float4*)Gall)[idx4] = s;
}

// ---------------------------------------------------------------------------
// Kernel 3: scaled Newton-Schulz, one block (512 thr, 8 waves) per matrix.
// Wave grid 2x4 (4 tile-rows x 2 tile-cols per wave) — 2 waves/SIMD.
// Per-block stats (trace, ||.||_F^2) computed from the G load registers.
// S = G/||G||_F + eps*I, eps = 2e-4 * trace/||G||_F.
// Iter k: W = Z*Y ; M = C1[k]*I - C2[k]*W (hi/lo) ; Y' = Y*M ; Z' = M*Z.
// Output: nuc = sqrt(s) * [ (1/s)tr(GZ) + (eps/2)tr(Z) - (eps^2/8)tr(Z^3) ].
// LDS: Yh,Yl,Mh,Ml,Z = 5 x 32KB = 160 KiB (scratch reuses Zb/Mh storage).
// ---------------------------------------------------------------------------
__global__ __launch_bounds__(512, 1) void ole_ns(const float* __restrict__ G,
                                                 float* __restrict__ nuc) {
  __shared__ short Yh[DIM * DIM];
  __shared__ short Yl[DIM * DIM];
  __shared__ short Mh[DIM * DIM];
  __shared__ short Ml[DIM * DIM];
  __shared__ short Zb[DIM * DIM];

  const int m_id = blockIdx.x;
  const int tid  = threadIdx.x;
  const int lane = tid & 63;
  const int quad = lane >> 4;
  const int wv   = tid >> 6;    // 0..7
  const int wr   = wv >> 2;     // 0..1 -> tile-rows 4*wr..4*wr+3
  const int wc   = wv & 3;      // 0..3 -> tile-cols 2*wc..2*wc+1

  const float4* Gm4 = (const float4*)(G + (size_t)m_id * DIM * DIM);

  // ---- load G (8 float4/thread), in-block trace + fro2 ----
  float4 gs[8];
  float tpart = 0.f, fpart = 0.f;
#pragma unroll
  for (int t = 0; t < 8; ++t) {
    int idx4 = tid + 512 * t;
    float4 v = Gm4[idx4];
    gs[t] = v;
    fpart += v.x * v.x + v.y * v.y + v.z * v.z + v.w * v.w;
    int flat = idx4 * 4, i = flat >> 7, j0 = flat & 127;
    if (j0 <= i && i < j0 + 4) tpart += ((const float*)&v)[i - j0];
  }
  for (int off = 32; off > 0; off >>= 1) {
    tpart += __shfl_down(tpart, off, 64);
    fpart += __shfl_down(fpart, off, 64);
  }
  float* redf = (float*)Zb;           // Zb not yet initialized
  if (lane == 0) { redf[wv] = tpart; redf[8 + wv] = fpart; }
  __syncthreads();
  float trace = 0.f, fro2 = 0.f;
#pragma unroll
  for (int w = 0; w < 8; ++w) { trace += redf[w]; fro2 += redf[8 + w]; }
  __syncthreads();                    // all reads of redf done -> Zb reusable

  float s = sqrtf(fro2);
  if (s < 1e-12f) s = 1.f;
  const float invs = 1.f / s;
  const float eps  = EPSN * trace * invs;

  // ---- init: Y0 = G/s + eps*I (hi/lo), Z0 = I ----
#pragma unroll
  for (int t = 0; t < 8; ++t) {
    int idx4 = tid + 512 * t;
    int flat = idx4 * 4, i = flat >> 7, j0 = flat & 127;
    s16x4 vh, vl;
#pragma unroll
    for (int e = 0; e < 4; ++e) {
      float x = ((const float*)&gs[t])[e] * invs + ((i == j0 + e) ? eps : 0.f);
      unsigned short hh = f2bf(x);
      vh[e] = (short)hh;
      vl[e] = (short)f2bf(x - bf2f(hh));
    }
    int idx = swz_idx(i, j0);
    *(s16x4*)(Yh + idx) = vh;
    *(s16x4*)(Yl + idx) = vl;
  }
  for (int grp = tid; grp < DIM * 16; grp += 512) {
    int i = grp >> 4, g = grp & 15;
    s16x8 v = (s16x8)0;
    if ((i >> 3) == g) v[i & 7] = (short)0x3F80;   // 1.0 bf16
    *(s16x8*)(Zb + i * 128 + ((g ^ (i & 15)) << 3)) = v;
  }
  __syncthreads();

  for (int it = 0; it < NITER; ++it) {
    const float kA = NS_C1[it];
    const float kB = NS_C2[it];

    // --- (a) W = Z*Y (Yh+Yl) ---
    f32x4 acc[4][2];
#pragma unroll
    for (int r = 0; r < 4; ++r)
#pragma unroll
      for (int c2 = 0; c2 < 2; ++c2) acc[r][c2] = (f32x4)0.f;
#pragma unroll
    for (int ks = 0; ks < 4; ++ks) {
      s16x8 a[4], bh[2], bl[2];
#pragma unroll
      for (int r = 0; r < 4; ++r) a[r] = load_frag(Zb, (4 * wr + r) * 16, ks, lane);
#pragma unroll
      for (int c2 = 0; c2 < 2; ++c2) {
        bh[c2] = load_frag(Yh, (2 * wc + c2) * 16, ks, lane);
        bl[c2] = load_frag(Yl, (2 * wc + c2) * 16, ks, lane);
      }
#pragma unroll
      for (int r = 0; r < 4; ++r)
#pragma unroll
        for (int c2 = 0; c2 < 2; ++c2) {
          acc[r][c2] = __builtin_amdgcn_mfma_f32_16x16x32_bf16(a[r], bh[c2], acc[r][c2], 0, 0, 0);
          acc[r][c2] = __builtin_amdgcn_mfma_f32_16x16x32_bf16(a[r], bl[c2], acc[r][c2], 0, 0, 0);
        }
    }
    // --- (b) M = kA*I - kB*W, clamp, hi/lo split, transposed store ---
#pragma unroll
    for (int r = 0; r < 4; ++r) {
      int ibase = (4 * wr + r) * 16 + quad * 4;
      int cg    = ibase >> 3;
#pragma unroll
      for (int c2 = 0; c2 < 2; ++c2) {
        int jg  = (2 * wc + c2) * 16 + (lane & 15);
        int idx = jg * 128 + ((cg ^ (jg & 15)) << 3) + (ibase & 7);
        s16x4 vh, vl;
#pragma unroll
        for (int e = 0; e < 4; ++e) {
          float mv = -kB * acc[r][c2][e] + ((ibase + e == jg) ? kA : 0.f);
          mv = fminf(fmaxf(mv, -4.f), 4.f);        // runaway insurance
          unsigned short hh = f2bf(mv);
          vh[e] = (short)hh;
          vl[e] = (short)f2bf(mv - bf2f(hh));
        }
        *(s16x4*)(Mh + idx) = vh;
        *(s16x4*)(Ml + idx) = vl;
      }
    }
    __syncthreads();

    // --- (c) Y' = Y*M (3 products), Z' = M*Z (2 products) ---
    f32x4 ay[4][2], az[4][2];
#pragma unroll
    for (int r = 0; r < 4; ++r)
#pragma unroll
      for (int c2 = 0; c2 < 2; ++c2) { ay[r][c2] = (f32x4)0.f; az[r][c2] = (f32x4)0.f; }
#pragma unroll
    for (int ks = 0; ks < 4; ++ks) {
      s16x8 aYh[4], aYl[4], aMh[4], aMl[4], bMh[2], bMl[2], bZ[2];
#pragma unroll
      for (int r = 0; r < 4; ++r) {
        int rb = (4 * wr + r) * 16;
        aYh[r] = load_frag(Yh, rb, ks, lane);
        aYl[r] = load_frag(Yl, rb, ks, lane);
        aMh[r] = load_frag(Mh, rb, ks, lane);
        aMl[r] = load_frag(Ml, rb, ks, lane);
      }
#pragma unroll
      for (int c2 = 0; c2 < 2; ++c2) {
        int cb = (2 * wc + c2) * 16;
        bMh[c2] = load_frag(Mh, cb, ks, lane);
        bMl[c2] = load_frag(Ml, cb, ks, lane);
        bZ[c2]  = load_frag(Zb, cb, ks, lane);
      }
#pragma unroll
      for (int r = 0; r < 4; ++r)
#pragma unroll
        for (int c2 = 0; c2 < 2; ++c2) {
          ay[r][c2] = __builtin_amdgcn_mfma_f32_16x16x32_bf16(aYh[r], bMh[c2], ay[r][c2], 0, 0, 0);
          ay[r][c2] = __builtin_amdgcn_mfma_f32_16x16x32_bf16(aYh[r], bMl[c2], ay[r][c2], 0, 0, 0);
          ay[r][c2] = __builtin_amdgcn_mfma_f32_16x16x32_bf16(aYl[r], bMh[c2], ay[r][c2], 0, 0, 0);
          az[r][c2] = __builtin_amdgcn_mfma_f32_16x16x32_bf16(aMh[r], bZ[c2],  az[r][c2], 0, 0, 0);
          az[r][c2] = __builtin_amdgcn_mfma_f32_16x16x32_bf16(aMl[r], bZ[c2],  az[r][c2], 0, 0, 0);
        }
    }
    __syncthreads();   // all reads of Y,Z done

    // --- (d) store Y' (hi/lo), Z' (single), transposed ---
#pragma unroll
    for (int r = 0; r < 4; ++r) {
      int ibase = (4 * wr + r) * 16 + quad * 4;
      int cg    = ibase >> 3;
#pragma unroll
      for (int c2 = 0; c2 < 2; ++c2) {
        int jg  = (2 * wc + c2) * 16 + (lane & 15);
        int idx = jg * 128 + ((cg ^ (jg & 15)) << 3) + (ibase & 7);
        s16x4 vh, vl, vz;
#pragma unroll
        for (int e = 0; e < 4; ++e) {
          float yv = ay[r][c2][e];
          unsigned short hh = f2bf(yv);
          vh[e] = (short)hh;
          vl[e] = (short)f2bf(yv - bf2f(hh));
          vz[e] = (short)f2bf(az[r][c2][e]);
        }
        *(s16x4*)(Yh + idx) = vh;
        *(s16x4*)(Yl + idx) = vl;
        *(s16x4*)(Zb + idx) = vz;
      }
    }
    __syncthreads();
  }

  // ---- traces: tr(GZ) (fp32 G anchor), tr(Z), tr(Z^3) ----
  float t_gz = 0.f, t_z = 0.f, t_z3 = 0.f;
#pragma unroll
  for (int t = 0; t < 8; ++t) {
    int idx4 = tid + 512 * t;
    int flat = idx4 * 4, i = flat >> 7, j0 = flat & 127;
    float4 g = Gm4[idx4];
    s16x4 zv = *(const s16x4*)(Zb + swz_idx(i, j0));
#pragma unroll
    for (int e = 0; e < 4; ++e) t_gz += ((const float*)&g)[e] * bf2f((unsigned short)zv[e]);
  }
  if (tid < DIM) t_z = bf2f((unsigned short)Zb[swz_idx(tid, tid)]);

  {  // U = Z*Z tile-wise; tr(Z^3) = sum U_ij * Z_ji
    f32x4 u[4][2];
#pragma unroll
    for (int r = 0; r < 4; ++r)
#pragma unroll
      for (int c2 = 0; c2 < 2; ++c2) u[r][c2] = (f32x4)0.f;
#pragma unroll
    for (int ks = 0; ks < 4; ++ks) {
      s16x8 a[4], b[2];
#pragma unroll
      for (int r = 0; r < 4; ++r) a[r] = load_frag(Zb, (4 * wr + r) * 16, ks, lane);
#pragma unroll
      for (int c2 = 0; c2 < 2; ++c2) b[c2] = load_frag(Zb, (2 * wc + c2) * 16, ks, lane);
#pragma unroll
      for (int r = 0; r < 4; ++r)
#pragma unroll
        for (int c2 = 0; c2 < 2; ++c2)
          u[r][c2] = __builtin_amdgcn_mfma_f32_16x16x32_bf16(a[r], b[c2], u[r][c2], 0, 0, 0);
    }
#pragma unroll
    for (int r = 0; r < 4; ++r) {
      int ibase = (4 * wr + r) * 16 + quad * 4;
      int cg    = ibase >> 3;
#pragma unroll
      for (int c2 = 0; c2 < 2; ++c2) {
        int jg  = (2 * wc + c2) * 16 + (lane & 15);
        int idx = jg * 128 + ((cg ^ (jg & 15)) << 3) + (ibase & 7);
        s16x4 zt = *(const s16x4*)(Zb + idx);
#pragma unroll
        for (int e = 0; e < 4; ++e) t_z3 += u[r][c2][e] * bf2f((unsigned short)zt[e]);
      }
    }
  }

  // block reduction (reuse Mh as scratch)
  for (int off = 32; off > 0; off >>= 1) {
    t_gz += __shfl_down(t_gz, off, 64);
    t_z  += __shfl_down(t_z,  off, 64);
    t_z3 += __shfl_down(t_z3, off, 64);
  }
  __syncthreads();
  float* red = (float*)Mh;
  if (lane == 0) { red[wv] = t_gz; red[8 + wv] = t_z; red[16 + wv] = t_z3; }
  __syncthreads();
  if (tid == 0) {
    float gz = 0.f, z1 = 0.f, z3 = 0.f;
#pragma unroll
    for (int w = 0; w < 8; ++w) { gz += red[w]; z1 += red[8 + w]; z3 += red[16 + w]; }
    float trsq = gz * invs + 0.5f * eps * z1 - 0.125f * eps * eps * z3;
    nuc[m_id] = sqrtf(s) * trsq;
  }
}

// ---------------------------------------------------------------------------
// Kernel 4: combine.  64 threads; sums 512 CE partials + 65 nuc values.
// ---------------------------------------------------------------------------
__global__ void ole_final(const float* __restrict__ nuc,
                          const float* __restrict__ cepart,
                          float* __restrict__ out) {
  int tid = threadIdx.x;
  float ce = 0.f;
#pragma unroll
  for (int k = 0; k < 8; ++k) ce += cepart[tid + 64 * k];
  float v = fmaxf(nuc[tid], DELTA_);
  for (int off = 32; off > 0; off >>= 1) {
    v  += __shfl_down(v, off, 64);
    ce += __shfl_down(ce, off, 64);
  }
  if (tid == 0) {
    float ole = (v - nuc[NCLS]) * (LAMBDA_ / (float)N_ROWS);
    out[0] = ole + ce / (float)N_ROWS;
  }
}

extern "C" void kernel_launch(void* const* d_in, const int* in_sizes, int n_in,
                              void* d_out, int out_size, void* d_ws, size_t ws_size,
                              hipStream_t stream) {
  const float* logits = (const float*)d_in[0];   // out  [8192,64]
  const float* feat   = (const float*)d_in[1];   // feat [8192,128]
  const int*   y      = (const int*)d_in[2];     // y    [8192]

  float* G      = (float*)d_ws;                        // 64 class mats
  float* Gall   = G + (size_t)NCLS * DIM * DIM;        // matrix index 64 (contiguous)
  float* nuc    = G + (size_t)NMAT * DIM * DIM;        // 65 floats
  float* cepart = nuc + NMAT;                          // 512 floats

  ole_gram_ce<<<NCLS + 128, 256, 0, stream>>>(feat, y, logits, G, cepart);
  ole_gall<<<16, 256, 0, stream>>>(G, Gall);
  ole_ns<<<NMAT, 512, 0, stream>>>(G, nuc);
  ole_final<<<1, 64, 0, stream>>>(nuc, cepart, (float*)d_out);
}